// Round 3
// baseline (446.322 us; speedup 1.0000x reference)
//
#include <hip/hip_runtime.h>

typedef unsigned int u32;
typedef unsigned short u16;
typedef __attribute__((ext_vector_type(8))) short bf16x8;
typedef __attribute__((ext_vector_type(4))) float f32x4;

#define T_TOK 12544   // 4*56*56
#define EMB   256
#define IMG   56
#define SCALE 0.17677669529663689f

__device__ __forceinline__ u32 bf16_rtne(float f) {
    u32 u = __builtin_bit_cast(u32, f);
    return (u + 0x7fffu + ((u >> 16) & 1u)) >> 16;
}
__device__ __forceinline__ float bf16_to_f(u32 h) { return __builtin_bit_cast(float, h << 16); }
__device__ __forceinline__ float bf_lo(u32 u) { return __builtin_bit_cast(float, u << 16); }
__device__ __forceinline__ float bf_hi(u32 u) { return __builtin_bit_cast(float, u & 0xffff0000u); }

// async global->LDS, 16B/lane; LDS dest must be wave-uniform base + lane*16
#define GLD16(g, l) __builtin_amdgcn_global_load_lds( \
    (const __attribute__((address_space(1))) u32*)(g), \
    (__attribute__((address_space(3))) u32*)(l), 16, 0, 0)

// ---------------------------------------------------------------------------
// Split fp32 -> bf16 hi/lo pairs: x and the 4 weight matrices.
// qkv weights stacked [768][256] (wq 0-255, wk 256-511, wv 512-767).
// ---------------------------------------------------------------------------
__global__ __launch_bounds__(256) void convert_kernel(
    const float* __restrict__ x, const float* __restrict__ wq, const float* __restrict__ wk,
    const float* __restrict__ wv, const float* __restrict__ wo,
    u16* __restrict__ xh, u16* __restrict__ xl,
    u16* __restrict__ bsh, u16* __restrict__ bsl,
    u16* __restrict__ boh, u16* __restrict__ bol) {
    const int i = blockIdx.x * 256 + threadIdx.x;
    const int NX4 = T_TOK * EMB / 4;
    float4 f;
    u16 *dh, *dl;
    int di;
    if (i < NX4) {
        f = ((const float4*)x)[i];
        dh = xh; dl = xl; di = i;
    } else {
        const int j = i - NX4;
        const int w = j >> 14, widx = j & 16383;
        const float* src = (w == 0) ? wq : (w == 1) ? wk : (w == 2) ? wv : wo;
        f = ((const float4*)src)[widx];
        if (w < 3) { dh = bsh; dl = bsl; di = (w << 14) + widx; }
        else       { dh = boh; dl = bol; di = widx; }
    }
    const float vf[4] = {f.x, f.y, f.z, f.w};
    ushort4 hv, lv;
    u16* hp = (u16*)&hv; u16* lp = (u16*)&lv;
    #pragma unroll
    for (int c = 0; c < 4; ++c) {
        const u32 h = bf16_rtne(vf[c]);
        hp[c] = (u16)h;
        lp[c] = (u16)bf16_rtne(vf[c] - bf16_to_f(h));
    }
    ((ushort4*)dh)[di] = hv;
    ((ushort4*)dl)[di] = lv;
}

// ---------------------------------------------------------------------------
// QKV GEMM, 128x128 tile, pass-inner: stage Ah/Al/Bh/Bl per k-tile once,
// run 3 split-bf16 MFMA passes. grid (6 nTiles, 98 mTiles) -> x-fast order
// keeps same-M blocks dispatch-adjacent for A-tile L2/L3 reuse.
// ---------------------------------------------------------------------------
__global__ __launch_bounds__(256) void qkv_mfma(
    const u16* __restrict__ xh, const u16* __restrict__ xl,
    const u16* __restrict__ bsh, const u16* __restrict__ bsl,
    const float* __restrict__ bq, const float* __restrict__ bk, const float* __restrict__ bv,
    float* __restrict__ qf, u16* __restrict__ kb, u16* __restrict__ vb) {
    __shared__ __attribute__((aligned(16))) u16 sAh[128 * 32];
    __shared__ __attribute__((aligned(16))) u16 sAl[128 * 32];
    __shared__ __attribute__((aligned(16))) u16 sBh[128 * 32];
    __shared__ __attribute__((aligned(16))) u16 sBl[128 * 32];
    const int nBase = blockIdx.x * 128;
    const int mBase = blockIdx.y * 128;
    const int tid = threadIdx.x, wv = tid >> 6, ln = tid & 63;
    const int lrow = ln & 15, lqd = ln >> 4;
    const int wm = (wv & 1) * 64, wn = (wv >> 1) * 64;
    const int c0 = wv * 128 + ln, r0 = c0 >> 2, kc0 = c0 & 3;
    const int c1 = c0 + 64,       r1 = c1 >> 2, kc1 = c1 & 3;
    const size_t gA0 = (size_t)(mBase + r0) * EMB + kc0 * 8;
    const size_t gA1 = (size_t)(mBase + r1) * EMB + kc1 * 8;
    const size_t gB0 = (size_t)(nBase + r0) * EMB + kc0 * 8;
    const size_t gB1 = (size_t)(nBase + r1) * EMB + kc1 * 8;
    const int l0 = (wv * 128) * 8, l1 = (wv * 128 + 64) * 8;

    f32x4 acc[4][4];
    #pragma unroll
    for (int mi = 0; mi < 4; ++mi)
        #pragma unroll
        for (int ni = 0; ni < 4; ++ni)
            acc[mi][ni] = (f32x4){0.f, 0.f, 0.f, 0.f};

    for (int kt = 0; kt < 8; ++kt) {
        const int k0 = kt * 32;
        GLD16(xh  + gA0 + k0, sAh + l0);
        GLD16(xh  + gA1 + k0, sAh + l1);
        GLD16(xl  + gA0 + k0, sAl + l0);
        GLD16(xl  + gA1 + k0, sAl + l1);
        GLD16(bsh + gB0 + k0, sBh + l0);
        GLD16(bsh + gB1 + k0, sBh + l1);
        GLD16(bsl + gB0 + k0, sBl + l0);
        GLD16(bsl + gB1 + k0, sBl + l1);
        __syncthreads();
        bf16x8 ah[4], al[4], bh[4], bl[4];
        #pragma unroll
        for (int mi = 0; mi < 4; ++mi) {
            ah[mi] = *(const bf16x8*)&sAh[(wm + mi * 16 + lrow) * 32 + lqd * 8];
            al[mi] = *(const bf16x8*)&sAl[(wm + mi * 16 + lrow) * 32 + lqd * 8];
        }
        #pragma unroll
        for (int ni = 0; ni < 4; ++ni) {
            bh[ni] = *(const bf16x8*)&sBh[(wn + ni * 16 + lrow) * 32 + lqd * 8];
            bl[ni] = *(const bf16x8*)&sBl[(wn + ni * 16 + lrow) * 32 + lqd * 8];
        }
        #pragma unroll
        for (int mi = 0; mi < 4; ++mi)
            #pragma unroll
            for (int ni = 0; ni < 4; ++ni) {
                acc[mi][ni] = __builtin_amdgcn_mfma_f32_16x16x32_bf16(ah[mi], bh[ni], acc[mi][ni], 0, 0, 0);
                acc[mi][ni] = __builtin_amdgcn_mfma_f32_16x16x32_bf16(al[mi], bh[ni], acc[mi][ni], 0, 0, 0);
                acc[mi][ni] = __builtin_amdgcn_mfma_f32_16x16x32_bf16(ah[mi], bl[ni], acc[mi][ni], 0, 0, 0);
            }
        __syncthreads();
    }

    const int which = nBase >> 8;   // 0=q, 1=k, 2=v (uniform)
    const float* bias = (which == 0) ? bq : (which == 1) ? bk : bv;
    #pragma unroll
    for (int ni = 0; ni < 4; ++ni) {
        const int ncol = nBase + wn + ni * 16 + lrow;
        const int c = ncol & 255;
        const float bz = bias[c];
        #pragma unroll
        for (int mi = 0; mi < 4; ++mi) {
            #pragma unroll
            for (int r = 0; r < 4; ++r) {
                const int row = mBase + wm + mi * 16 + lqd * 4 + r;
                const float val = acc[mi][ni][r] + bz;
                if (which == 0)      qf[(size_t)row * EMB + c] = val;
                else if (which == 1) kb[(size_t)row * EMB + c] = (u16)bf16_rtne(val);
                else                 vb[(size_t)row * EMB + c] = (u16)bf16_rtne(val);
            }
        }
    }
}

// ---------------------------------------------------------------------------
// Out-projection, 64x128 tile (grid (2,196) = 392 blocks for CU fill).
// Each wave: all 64 M rows x 32 N cols (acc[4][2]).
// ---------------------------------------------------------------------------
__global__ __launch_bounds__(256) void out_mfma(
    const u16* __restrict__ aoh, const u16* __restrict__ aol,
    const u16* __restrict__ boh, const u16* __restrict__ bol,
    const float* __restrict__ bo, float* __restrict__ out) {
    __shared__ __attribute__((aligned(16))) u16 sAh[64 * 32];
    __shared__ __attribute__((aligned(16))) u16 sAl[64 * 32];
    __shared__ __attribute__((aligned(16))) u16 sBh[128 * 32];
    __shared__ __attribute__((aligned(16))) u16 sBl[128 * 32];
    const int nBase = blockIdx.x * 128;
    const int mBase = blockIdx.y * 64;
    const int tid = threadIdx.x, wv = tid >> 6, ln = tid & 63;
    const int lrow = ln & 15, lqd = ln >> 4;
    const int cA = wv * 64 + ln, rA = cA >> 2, kcA = cA & 3;
    const size_t gA = (size_t)(mBase + rA) * EMB + kcA * 8;
    const int lA = (wv * 64) * 8;
    const int c0 = wv * 128 + ln, r0 = c0 >> 2, kc0 = c0 & 3;
    const int c1 = c0 + 64,       r1 = c1 >> 2, kc1 = c1 & 3;
    const size_t gB0 = (size_t)(nBase + r0) * EMB + kc0 * 8;
    const size_t gB1 = (size_t)(nBase + r1) * EMB + kc1 * 8;
    const int l0 = (wv * 128) * 8, l1 = (wv * 128 + 64) * 8;

    f32x4 acc[4][2];
    #pragma unroll
    for (int mi = 0; mi < 4; ++mi)
        #pragma unroll
        for (int ni = 0; ni < 2; ++ni)
            acc[mi][ni] = (f32x4){0.f, 0.f, 0.f, 0.f};

    for (int kt = 0; kt < 8; ++kt) {
        const int k0 = kt * 32;
        GLD16(aoh + gA + k0, sAh + lA);
        GLD16(aol + gA + k0, sAl + lA);
        GLD16(boh + gB0 + k0, sBh + l0);
        GLD16(boh + gB1 + k0, sBh + l1);
        GLD16(bol + gB0 + k0, sBl + l0);
        GLD16(bol + gB1 + k0, sBl + l1);
        __syncthreads();
        bf16x8 ah[4], al[4], bh[2], bl[2];
        #pragma unroll
        for (int mi = 0; mi < 4; ++mi) {
            ah[mi] = *(const bf16x8*)&sAh[(mi * 16 + lrow) * 32 + lqd * 8];
            al[mi] = *(const bf16x8*)&sAl[(mi * 16 + lrow) * 32 + lqd * 8];
        }
        #pragma unroll
        for (int ni = 0; ni < 2; ++ni) {
            bh[ni] = *(const bf16x8*)&sBh[(wv * 32 + ni * 16 + lrow) * 32 + lqd * 8];
            bl[ni] = *(const bf16x8*)&sBl[(wv * 32 + ni * 16 + lrow) * 32 + lqd * 8];
        }
        #pragma unroll
        for (int mi = 0; mi < 4; ++mi)
            #pragma unroll
            for (int ni = 0; ni < 2; ++ni) {
                acc[mi][ni] = __builtin_amdgcn_mfma_f32_16x16x32_bf16(ah[mi], bh[ni], acc[mi][ni], 0, 0, 0);
                acc[mi][ni] = __builtin_amdgcn_mfma_f32_16x16x32_bf16(al[mi], bh[ni], acc[mi][ni], 0, 0, 0);
                acc[mi][ni] = __builtin_amdgcn_mfma_f32_16x16x32_bf16(ah[mi], bl[ni], acc[mi][ni], 0, 0, 0);
            }
        __syncthreads();
    }

    #pragma unroll
    for (int ni = 0; ni < 2; ++ni) {
        const int ncol = nBase + wv * 32 + ni * 16 + lrow;
        const float bz = bo[ncol];
        #pragma unroll
        for (int mi = 0; mi < 4; ++mi) {
            #pragma unroll
            for (int r = 0; r < 4; ++r) {
                const int row = mBase + mi * 16 + lqd * 4 + r;
                out[(size_t)row * EMB + ncol] = acc[mi][ni][r] + bz;
            }
        }
    }
}

// ---------------------------------------------------------------------------
// Attention v3: 128 thr = 2 waves = 2 heads, 8x8 pixel tile. One 25 KB LDS
// buffer [196 halo rows][32 dwords]; row = 2 heads x 4 dim-quads, physical
// quad = logical ^ (p&7) => neighbor reads are 4 conflict-free ds_read_b128.
// Phase-split: stage K -> QK -> barrier -> stage V (same LDS) -> PV.
// OOB halo zero-filled => logit exactly 0 (F.unfold zero padding semantics).
// ---------------------------------------------------------------------------
__global__ __launch_bounds__(128) void attn_kernel(
    const float* __restrict__ qf, const u16* __restrict__ kb, const u16* __restrict__ vb,
    u16* __restrict__ aoh, u16* __restrict__ aol) {
    __shared__ __attribute__((aligned(16))) u32 sT[196 * 32];   // 25088 B
    const int tid = threadIdx.x;
    const int wv = tid >> 6, ln = tid & 63;
    const int img = blockIdx.z >> 2;
    const int hg  = (blockIdx.z & 3) * 2;
    const int ty0 = blockIdx.y * 8, tx0 = blockIdx.x * 8;

    // ---- stage K ----
    #pragma unroll
    for (int it = 0; it < 13; ++it) {
        const int i = it * 128 + tid;
        if (i < 1568) {
            const int p = i >> 3, pq = i & 7;
            const int q = pq ^ (p & 7);
            const int h = q >> 2, dq = q & 3;
            const int pyh = p / 14, pxh = p - pyh * 14;
            const int gy = ty0 - 3 + pyh, gx = tx0 - 3 + pxh;
            u32* lbase = sT + (it * 128 + wv * 64) * 4;
            if ((unsigned)gy < 56u && (unsigned)gx < 56u) {
                const size_t tt = ((size_t)img * IMG + gy) * IMG + gx;
                GLD16(kb + tt * EMB + (hg + h) * 32 + dq * 8, lbase);
            } else {
                *(uint4*)&sT[p * 32 + 4 * pq] = (uint4){0u, 0u, 0u, 0u};
            }
        }
    }
    __syncthreads();

    const int hl = wv, head = hg + hl;
    const int py = ln >> 3, px = ln & 7;
    const size_t t = ((size_t)img * IMG + ty0 + py) * IMG + tx0 + px;

    float qr[32];
    const float4* qs = (const float4*)&qf[t * EMB + head * 32];
    #pragma unroll
    for (int i = 0; i < 8; ++i) {
        const float4 f = qs[i];
        qr[4*i] = f.x; qr[4*i+1] = f.y; qr[4*i+2] = f.z; qr[4*i+3] = f.w;
    }

    float lg[49];
    #pragma unroll
    for (int jy = 0; jy < 7; ++jy)
        #pragma unroll
        for (int jx = 0; jx < 7; ++jx) {
            const int p = (py + jy) * 14 + px + jx;
            const int pb = p * 32, ps = p & 7;
            float a0 = 0.f, a1 = 0.f;
            #pragma unroll
            for (int dq = 0; dq < 4; ++dq) {
                const uint4 kq = *(const uint4*)&sT[pb + 4 * ((hl * 4 + dq) ^ ps)];
                a0 += qr[8*dq+0] * bf_lo(kq.x); a1 += qr[8*dq+1] * bf_hi(kq.x);
                a0 += qr[8*dq+2] * bf_lo(kq.y); a1 += qr[8*dq+3] * bf_hi(kq.y);
                a0 += qr[8*dq+4] * bf_lo(kq.z); a1 += qr[8*dq+5] * bf_hi(kq.z);
                a0 += qr[8*dq+6] * bf_lo(kq.w); a1 += qr[8*dq+7] * bf_hi(kq.w);
            }
            lg[jy * 7 + jx] = (a0 + a1) * SCALE;
        }
    __syncthreads();   // all K reads done before V overwrites

    // ---- stage V ----
    #pragma unroll
    for (int it = 0; it < 13; ++it) {
        const int i = it * 128 + tid;
        if (i < 1568) {
            const int p = i >> 3, pq = i & 7;
            const int q = pq ^ (p & 7);
            const int h = q >> 2, dq = q & 3;
            const int pyh = p / 14, pxh = p - pyh * 14;
            const int gy = ty0 - 3 + pyh, gx = tx0 - 3 + pxh;
            u32* lbase = sT + (it * 128 + wv * 64) * 4;
            if ((unsigned)gy < 56u && (unsigned)gx < 56u) {
                const size_t tt = ((size_t)img * IMG + gy) * IMG + gx;
                GLD16(vb + tt * EMB + (hg + h) * 32 + dq * 8, lbase);
            } else {
                *(uint4*)&sT[p * 32 + 4 * pq] = (uint4){0u, 0u, 0u, 0u};
            }
        }
    }
    __syncthreads();

    float m = lg[0];
    #pragma unroll
    for (int j = 1; j < 49; ++j) m = fmaxf(m, lg[j]);
    float s = 0.f;
    #pragma unroll
    for (int j = 0; j < 49; ++j) { lg[j] = __expf(lg[j] - m); s += lg[j]; }
    const float inv = 1.0f / s;

    float o[32] = {};
    #pragma unroll
    for (int jy = 0; jy < 7; ++jy)
        #pragma unroll
        for (int jx = 0; jx < 7; ++jx) {
            const int p = (py + jy) * 14 + px + jx;
            const int pb = p * 32, ps = p & 7;
            const float wgt = lg[jy * 7 + jx];
            #pragma unroll
            for (int dq = 0; dq < 4; ++dq) {
                const uint4 vq = *(const uint4*)&sT[pb + 4 * ((hl * 4 + dq) ^ ps)];
                o[8*dq+0] += wgt * bf_lo(vq.x); o[8*dq+1] += wgt * bf_hi(vq.x);
                o[8*dq+2] += wgt * bf_lo(vq.y); o[8*dq+3] += wgt * bf_hi(vq.y);
                o[8*dq+4] += wgt * bf_lo(vq.z); o[8*dq+5] += wgt * bf_hi(vq.z);
                o[8*dq+6] += wgt * bf_lo(vq.w); o[8*dq+7] += wgt * bf_hi(vq.w);
            }
        }

    u16* ohp = &aoh[t * EMB + head * 32];
    u16* olp = &aol[t * EMB + head * 32];
    #pragma unroll
    for (int g = 0; g < 8; ++g) {
        ushort4 hv, lv;
        u16* hp = (u16*)&hv; u16* lp = (u16*)&lv;
        #pragma unroll
        for (int c = 0; c < 4; ++c) {
            const float v = o[g * 4 + c] * inv;
            const u32 h = bf16_rtne(v);
            hp[c] = (u16)h;
            lp[c] = (u16)bf16_rtne(v - bf16_to_f(h));
        }
        ((ushort4*)ohp)[g] = hv;
        ((ushort4*)olp)[g] = lv;
    }
}

extern "C" void kernel_launch(void* const* d_in, const int* in_sizes, int n_in,
                              void* d_out, int out_size, void* d_ws, size_t ws_size,
                              hipStream_t stream) {
    const float* x  = (const float*)d_in[0];
    const float* wq = (const float*)d_in[1];
    const float* wk = (const float*)d_in[2];
    const float* wv = (const float*)d_in[3];
    const float* wo = (const float*)d_in[4];
    const float* bq = (const float*)d_in[5];
    const float* bk = (const float*)d_in[6];
    const float* bv = (const float*)d_in[7];
    const float* bo = (const float*)d_in[8];
    float* out = (float*)d_out;

    char* ws = (char*)d_ws;
    u16*   xh  = (u16*)(ws);                  // 6,422,528 B
    u16*   xl  = (u16*)(ws + 6422528);        // 6,422,528 B
    float* qf  = (float*)(ws + 12845056);     // 12,845,056 B
    u16*   kb  = (u16*)(ws + 25690112);       // 6,422,528 B
    u16*   vb  = (u16*)(ws + 32112640);       // 6,422,528 B
    u16*   bsh = (u16*)(ws + 38535168);       // 393,216 B
    u16*   bsl = (u16*)(ws + 38928384);       // 393,216 B
    u16*   boh = (u16*)(ws + 39321600);       // 131,072 B
    u16*   bol = (u16*)(ws + 39452672);       // 131,072 B
    // xh/xl dead after qkv_mfma; attn reuses them as split-bf16 output
    u16* aoh = xh;
    u16* aol = xl;

    convert_kernel<<<3392, 256, 0, stream>>>(x, wq, wk, wv, wo, xh, xl, bsh, bsl, boh, bol);
    qkv_mfma<<<dim3(6, 98), 256, 0, stream>>>(xh, xl, bsh, bsl, bq, bk, bv, qf, kb, vb);
    attn_kernel<<<dim3(7, 7, 16), 128, 0, stream>>>(qf, kb, vb, aoh, aol);
    out_mfma<<<dim3(2, 196), 256, 0, stream>>>(aoh, aol, boh, bol, bo, out);
}

// Round 4
// 223.364 us; speedup vs baseline: 1.9982x; 1.9982x over previous
//
#include <hip/hip_runtime.h>

typedef unsigned int u32;
typedef unsigned short u16;
typedef __attribute__((ext_vector_type(8))) short bf16x8;
typedef __attribute__((ext_vector_type(4))) float f32x4;

#define T_TOK 12544   // 4*56*56
#define EMB   256
#define IMG   56
#define SCALE 0.17677669529663689f

__device__ __forceinline__ u32 bf16_rtne(float f) {
    u32 u = __builtin_bit_cast(u32, f);
    return (u + 0x7fffu + ((u >> 16) & 1u)) >> 16;
}
__device__ __forceinline__ float bf16_to_f(u32 h) { return __builtin_bit_cast(float, h << 16); }
__device__ __forceinline__ float bf_lo(u32 u) { return __builtin_bit_cast(float, u << 16); }
__device__ __forceinline__ float bf_hi(u32 u) { return __builtin_bit_cast(float, u & 0xffff0000u); }

// async global->LDS, 16B/lane; LDS dest must be wave-uniform base + lane*16
#define GLD16(g, l) __builtin_amdgcn_global_load_lds( \
    (const __attribute__((address_space(1))) u32*)(g), \
    (__attribute__((address_space(3))) u32*)(l), 16, 0, 0)

// ---------------------------------------------------------------------------
// Split fp32 -> bf16 hi/lo pairs: x and the 4 weight matrices.
// qkv weights stacked [768][256] (wq 0-255, wk 256-511, wv 512-767).
// ---------------------------------------------------------------------------
__global__ __launch_bounds__(256) void convert_kernel(
    const float* __restrict__ x, const float* __restrict__ wq, const float* __restrict__ wk,
    const float* __restrict__ wv, const float* __restrict__ wo,
    u16* __restrict__ xh, u16* __restrict__ xl,
    u16* __restrict__ bsh, u16* __restrict__ bsl,
    u16* __restrict__ boh, u16* __restrict__ bol) {
    const int i = blockIdx.x * 256 + threadIdx.x;
    const int NX4 = T_TOK * EMB / 4;
    float4 f;
    u16 *dh, *dl;
    int di;
    if (i < NX4) {
        f = ((const float4*)x)[i];
        dh = xh; dl = xl; di = i;
    } else {
        const int j = i - NX4;
        const int w = j >> 14, widx = j & 16383;
        const float* src = (w == 0) ? wq : (w == 1) ? wk : (w == 2) ? wv : wo;
        f = ((const float4*)src)[widx];
        if (w < 3) { dh = bsh; dl = bsl; di = (w << 14) + widx; }
        else       { dh = boh; dl = bol; di = widx; }
    }
    const float vf[4] = {f.x, f.y, f.z, f.w};
    ushort4 hv, lv;
    u16* hp = (u16*)&hv; u16* lp = (u16*)&lv;
    #pragma unroll
    for (int c = 0; c < 4; ++c) {
        const u32 h = bf16_rtne(vf[c]);
        hp[c] = (u16)h;
        lp[c] = (u16)bf16_rtne(vf[c] - bf16_to_f(h));
    }
    ((ushort4*)dh)[di] = hv;
    ((ushort4*)dl)[di] = lv;
}

// ---------------------------------------------------------------------------
// QKV GEMM, 128x128 tile, pass-inner: stage Ah/Al/Bh/Bl per k-tile once,
// run 3 split-bf16 MFMA passes. grid (6 nTiles, 98 mTiles).
// ---------------------------------------------------------------------------
__global__ __launch_bounds__(256) void qkv_mfma(
    const u16* __restrict__ xh, const u16* __restrict__ xl,
    const u16* __restrict__ bsh, const u16* __restrict__ bsl,
    const float* __restrict__ bq, const float* __restrict__ bk, const float* __restrict__ bv,
    float* __restrict__ qf, u16* __restrict__ kb, u16* __restrict__ vb) {
    __shared__ __attribute__((aligned(16))) u16 sAh[128 * 32];
    __shared__ __attribute__((aligned(16))) u16 sAl[128 * 32];
    __shared__ __attribute__((aligned(16))) u16 sBh[128 * 32];
    __shared__ __attribute__((aligned(16))) u16 sBl[128 * 32];
    const int nBase = blockIdx.x * 128;
    const int mBase = blockIdx.y * 128;
    const int tid = threadIdx.x, wv = tid >> 6, ln = tid & 63;
    const int lrow = ln & 15, lqd = ln >> 4;
    const int wm = (wv & 1) * 64, wn = (wv >> 1) * 64;
    const int c0 = wv * 128 + ln, r0 = c0 >> 2, kc0 = c0 & 3;
    const int c1 = c0 + 64,       r1 = c1 >> 2, kc1 = c1 & 3;
    const size_t gA0 = (size_t)(mBase + r0) * EMB + kc0 * 8;
    const size_t gA1 = (size_t)(mBase + r1) * EMB + kc1 * 8;
    const size_t gB0 = (size_t)(nBase + r0) * EMB + kc0 * 8;
    const size_t gB1 = (size_t)(nBase + r1) * EMB + kc1 * 8;
    const int l0 = (wv * 128) * 8, l1 = (wv * 128 + 64) * 8;

    f32x4 acc[4][4];
    #pragma unroll
    for (int mi = 0; mi < 4; ++mi)
        #pragma unroll
        for (int ni = 0; ni < 4; ++ni)
            acc[mi][ni] = (f32x4){0.f, 0.f, 0.f, 0.f};

    for (int kt = 0; kt < 8; ++kt) {
        const int k0 = kt * 32;
        GLD16(xh  + gA0 + k0, sAh + l0);
        GLD16(xh  + gA1 + k0, sAh + l1);
        GLD16(xl  + gA0 + k0, sAl + l0);
        GLD16(xl  + gA1 + k0, sAl + l1);
        GLD16(bsh + gB0 + k0, sBh + l0);
        GLD16(bsh + gB1 + k0, sBh + l1);
        GLD16(bsl + gB0 + k0, sBl + l0);
        GLD16(bsl + gB1 + k0, sBl + l1);
        __syncthreads();
        bf16x8 ah[4], al[4], bh[4], bl[4];
        #pragma unroll
        for (int mi = 0; mi < 4; ++mi) {
            ah[mi] = *(const bf16x8*)&sAh[(wm + mi * 16 + lrow) * 32 + lqd * 8];
            al[mi] = *(const bf16x8*)&sAl[(wm + mi * 16 + lrow) * 32 + lqd * 8];
        }
        #pragma unroll
        for (int ni = 0; ni < 4; ++ni) {
            bh[ni] = *(const bf16x8*)&sBh[(wn + ni * 16 + lrow) * 32 + lqd * 8];
            bl[ni] = *(const bf16x8*)&sBl[(wn + ni * 16 + lrow) * 32 + lqd * 8];
        }
        #pragma unroll
        for (int mi = 0; mi < 4; ++mi)
            #pragma unroll
            for (int ni = 0; ni < 4; ++ni) {
                acc[mi][ni] = __builtin_amdgcn_mfma_f32_16x16x32_bf16(ah[mi], bh[ni], acc[mi][ni], 0, 0, 0);
                acc[mi][ni] = __builtin_amdgcn_mfma_f32_16x16x32_bf16(al[mi], bh[ni], acc[mi][ni], 0, 0, 0);
                acc[mi][ni] = __builtin_amdgcn_mfma_f32_16x16x32_bf16(ah[mi], bl[ni], acc[mi][ni], 0, 0, 0);
            }
        __syncthreads();
    }

    const int which = nBase >> 8;   // 0=q, 1=k, 2=v (uniform)
    const float* bias = (which == 0) ? bq : (which == 1) ? bk : bv;
    #pragma unroll
    for (int ni = 0; ni < 4; ++ni) {
        const int ncol = nBase + wn + ni * 16 + lrow;
        const int c = ncol & 255;
        const float bz = bias[c];
        #pragma unroll
        for (int mi = 0; mi < 4; ++mi) {
            #pragma unroll
            for (int r = 0; r < 4; ++r) {
                const int row = mBase + wm + mi * 16 + lqd * 4 + r;
                const float val = acc[mi][ni][r] + bz;
                if (which == 0)      qf[(size_t)row * EMB + c] = val;
                else if (which == 1) kb[(size_t)row * EMB + c] = (u16)bf16_rtne(val);
                else                 vb[(size_t)row * EMB + c] = (u16)bf16_rtne(val);
            }
        }
    }
}

// ---------------------------------------------------------------------------
// Out-projection, 64x128 tile (grid (2,196) = 392 blocks for CU fill).
// ---------------------------------------------------------------------------
__global__ __launch_bounds__(256) void out_mfma(
    const u16* __restrict__ aoh, const u16* __restrict__ aol,
    const u16* __restrict__ boh, const u16* __restrict__ bol,
    const float* __restrict__ bo, float* __restrict__ out) {
    __shared__ __attribute__((aligned(16))) u16 sAh[64 * 32];
    __shared__ __attribute__((aligned(16))) u16 sAl[64 * 32];
    __shared__ __attribute__((aligned(16))) u16 sBh[128 * 32];
    __shared__ __attribute__((aligned(16))) u16 sBl[128 * 32];
    const int nBase = blockIdx.x * 128;
    const int mBase = blockIdx.y * 64;
    const int tid = threadIdx.x, wv = tid >> 6, ln = tid & 63;
    const int lrow = ln & 15, lqd = ln >> 4;
    const int cA = wv * 64 + ln, rA = cA >> 2, kcA = cA & 3;
    const size_t gA = (size_t)(mBase + rA) * EMB + kcA * 8;
    const int lA = (wv * 64) * 8;
    const int c0 = wv * 128 + ln, r0 = c0 >> 2, kc0 = c0 & 3;
    const int c1 = c0 + 64,       r1 = c1 >> 2, kc1 = c1 & 3;
    const size_t gB0 = (size_t)(nBase + r0) * EMB + kc0 * 8;
    const size_t gB1 = (size_t)(nBase + r1) * EMB + kc1 * 8;
    const int l0 = (wv * 128) * 8, l1 = (wv * 128 + 64) * 8;

    f32x4 acc[4][2];
    #pragma unroll
    for (int mi = 0; mi < 4; ++mi)
        #pragma unroll
        for (int ni = 0; ni < 2; ++ni)
            acc[mi][ni] = (f32x4){0.f, 0.f, 0.f, 0.f};

    for (int kt = 0; kt < 8; ++kt) {
        const int k0 = kt * 32;
        GLD16(aoh + gA + k0, sAh + lA);
        GLD16(aol + gA + k0, sAl + lA);
        GLD16(boh + gB0 + k0, sBh + l0);
        GLD16(boh + gB1 + k0, sBh + l1);
        GLD16(bol + gB0 + k0, sBl + l0);
        GLD16(bol + gB1 + k0, sBl + l1);
        __syncthreads();
        bf16x8 ah[4], al[4], bh[2], bl[2];
        #pragma unroll
        for (int mi = 0; mi < 4; ++mi) {
            ah[mi] = *(const bf16x8*)&sAh[(mi * 16 + lrow) * 32 + lqd * 8];
            al[mi] = *(const bf16x8*)&sAl[(mi * 16 + lrow) * 32 + lqd * 8];
        }
        #pragma unroll
        for (int ni = 0; ni < 2; ++ni) {
            bh[ni] = *(const bf16x8*)&sBh[(wv * 32 + ni * 16 + lrow) * 32 + lqd * 8];
            bl[ni] = *(const bf16x8*)&sBl[(wv * 32 + ni * 16 + lrow) * 32 + lqd * 8];
        }
        #pragma unroll
        for (int mi = 0; mi < 4; ++mi)
            #pragma unroll
            for (int ni = 0; ni < 2; ++ni) {
                acc[mi][ni] = __builtin_amdgcn_mfma_f32_16x16x32_bf16(ah[mi], bh[ni], acc[mi][ni], 0, 0, 0);
                acc[mi][ni] = __builtin_amdgcn_mfma_f32_16x16x32_bf16(al[mi], bh[ni], acc[mi][ni], 0, 0, 0);
                acc[mi][ni] = __builtin_amdgcn_mfma_f32_16x16x32_bf16(ah[mi], bl[ni], acc[mi][ni], 0, 0, 0);
            }
        __syncthreads();
    }

    #pragma unroll
    for (int ni = 0; ni < 2; ++ni) {
        const int ncol = nBase + wv * 32 + ni * 16 + lrow;
        const float bz = bo[ncol];
        #pragma unroll
        for (int mi = 0; mi < 4; ++mi) {
            #pragma unroll
            for (int r = 0; r < 4; ++r) {
                const int row = mBase + mi * 16 + lqd * 4 + r;
                out[(size_t)row * EMB + ncol] = acc[mi][ni][r] + bz;
            }
        }
    }
}

// ---------------------------------------------------------------------------
// Attention v4: 128 thr = 2 waves = 2 heads, 8x8 pixel tile. Phase-split K/V
// in one 25 KB buffer, pair-major layout: per head [f=0..7][p=0..195][2 u32]
// (row stride 392 dwords). Neighbor reads = 8 ds_read_b64; bank =
// (8f+2p)%32 varies with p -> exactly 4 dwords/bank/wave (conflict-free min).
// Staged via uint4 global load + 2 ds_write_b64 (keeps VGPR low; r3's
// unrolled-uint4-read version spilled at 256 VGPRs).
// OOB halo zero-filled => logit exactly 0 (F.unfold zero padding semantics).
// ---------------------------------------------------------------------------
__global__ __launch_bounds__(128) void attn_kernel(
    const float* __restrict__ qf, const u16* __restrict__ kb, const u16* __restrict__ vb,
    u16* __restrict__ aoh, u16* __restrict__ aol) {
    __shared__ __attribute__((aligned(16))) u32 sT[2 * 3136];   // 25088 B
    const int tid = threadIdx.x;
    const int img = blockIdx.z >> 2;
    const int hg  = (blockIdx.z & 3) * 2;
    const int ty0 = blockIdx.y * 8, tx0 = blockIdx.x * 8;

    // ---- stage K ----
    for (int i = tid; i < 1568; i += 128) {
        const int c = i & 3, rem = i >> 2;
        const int hl = (rem >= 196) ? 1 : 0;
        const int p = rem - 196 * hl;
        const int pyh = p / 14, pxh = p - pyh * 14;
        const int gy = ty0 - 3 + pyh, gx = tx0 - 3 + pxh;
        u32* d0 = &sT[hl * 3136 + (2 * c) * 392 + 2 * p];
        if ((unsigned)gy < 56u && (unsigned)gx < 56u) {
            const size_t tt = ((size_t)img * IMG + gy) * IMG + gx;
            const uint4 u = *(const uint4*)&kb[tt * EMB + (hg + hl) * 32 + c * 8];
            *(uint2*)d0         = (uint2){u.x, u.y};
            *(uint2*)(d0 + 392) = (uint2){u.z, u.w};
        } else {
            *(uint2*)d0         = (uint2){0u, 0u};
            *(uint2*)(d0 + 392) = (uint2){0u, 0u};
        }
    }
    __syncthreads();

    const int hl = tid >> 6, ln = tid & 63;
    const int head = hg + hl;
    const int py = ln >> 3, px = ln & 7;
    const size_t t = ((size_t)img * IMG + ty0 + py) * IMG + tx0 + px;

    float qr[32];
    const float4* qs = (const float4*)&qf[t * EMB + head * 32];
    #pragma unroll
    for (int i = 0; i < 8; ++i) {
        const float4 f = qs[i];
        qr[4*i] = f.x; qr[4*i+1] = f.y; qr[4*i+2] = f.z; qr[4*i+3] = f.w;
    }

    const u32* hb = &sT[hl * 3136];

    float lg[49];
    #pragma unroll
    for (int jy = 0; jy < 7; ++jy)
        #pragma unroll
        for (int jx = 0; jx < 7; ++jx) {
            const int p2 = 2 * ((py + jy) * 14 + px + jx);
            float a0 = 0.f, a1 = 0.f;
            #pragma unroll
            for (int f = 0; f < 8; ++f) {
                const uint2 u = *(const uint2*)&hb[f * 392 + p2];
                a0 += qr[4*f]   * bf_lo(u.x); a1 += qr[4*f+1] * bf_hi(u.x);
                a0 += qr[4*f+2] * bf_lo(u.y); a1 += qr[4*f+3] * bf_hi(u.y);
            }
            lg[jy * 7 + jx] = (a0 + a1) * SCALE;
        }
    __syncthreads();   // all K reads done before V overwrites

    // ---- stage V ----
    for (int i = tid; i < 1568; i += 128) {
        const int c = i & 3, rem = i >> 2;
        const int hv2 = (rem >= 196) ? 1 : 0;
        const int p = rem - 196 * hv2;
        const int pyh = p / 14, pxh = p - pyh * 14;
        const int gy = ty0 - 3 + pyh, gx = tx0 - 3 + pxh;
        u32* d0 = &sT[hv2 * 3136 + (2 * c) * 392 + 2 * p];
        if ((unsigned)gy < 56u && (unsigned)gx < 56u) {
            const size_t tt = ((size_t)img * IMG + gy) * IMG + gx;
            const uint4 u = *(const uint4*)&vb[tt * EMB + (hg + hv2) * 32 + c * 8];
            *(uint2*)d0         = (uint2){u.x, u.y};
            *(uint2*)(d0 + 392) = (uint2){u.z, u.w};
        } else {
            *(uint2*)d0         = (uint2){0u, 0u};
            *(uint2*)(d0 + 392) = (uint2){0u, 0u};
        }
    }

    // softmax (VALU only; overlaps other waves' V staging before the barrier)
    float m = lg[0];
    #pragma unroll
    for (int j = 1; j < 49; ++j) m = fmaxf(m, lg[j]);
    float s = 0.f;
    #pragma unroll
    for (int j = 0; j < 49; ++j) { lg[j] = __expf(lg[j] - m); s += lg[j]; }
    const float inv = 1.0f / s;
    __syncthreads();

    float o[32] = {};
    #pragma unroll
    for (int jy = 0; jy < 7; ++jy)
        #pragma unroll
        for (int jx = 0; jx < 7; ++jx) {
            const int p2 = 2 * ((py + jy) * 14 + px + jx);
            const float wgt = lg[jy * 7 + jx];
            #pragma unroll
            for (int f = 0; f < 8; ++f) {
                const uint2 u = *(const uint2*)&hb[f * 392 + p2];
                o[4*f]   += wgt * bf_lo(u.x); o[4*f+1] += wgt * bf_hi(u.x);
                o[4*f+2] += wgt * bf_lo(u.y); o[4*f+3] += wgt * bf_hi(u.y);
            }
        }

    u16* ohp = &aoh[t * EMB + head * 32];
    u16* olp = &aol[t * EMB + head * 32];
    #pragma unroll
    for (int g = 0; g < 8; ++g) {
        ushort4 hv, lv;
        u16* hp = (u16*)&hv; u16* lp = (u16*)&lv;
        #pragma unroll
        for (int c = 0; c < 4; ++c) {
            const float v = o[g * 4 + c] * inv;
            const u32 h = bf16_rtne(v);
            hp[c] = (u16)h;
            lp[c] = (u16)bf16_rtne(v - bf16_to_f(h));
        }
        ((ushort4*)ohp)[g] = hv;
        ((ushort4*)olp)[g] = lv;
    }
}

extern "C" void kernel_launch(void* const* d_in, const int* in_sizes, int n_in,
                              void* d_out, int out_size, void* d_ws, size_t ws_size,
                              hipStream_t stream) {
    const float* x  = (const float*)d_in[0];
    const float* wq = (const float*)d_in[1];
    const float* wk = (const float*)d_in[2];
    const float* wv = (const float*)d_in[3];
    const float* wo = (const float*)d_in[4];
    const float* bq = (const float*)d_in[5];
    const float* bk = (const float*)d_in[6];
    const float* bv = (const float*)d_in[7];
    const float* bo = (const float*)d_in[8];
    float* out = (float*)d_out;

    char* ws = (char*)d_ws;
    u16*   xh  = (u16*)(ws);                  // 6,422,528 B
    u16*   xl  = (u16*)(ws + 6422528);        // 6,422,528 B
    float* qf  = (float*)(ws + 12845056);     // 12,845,056 B
    u16*   kb  = (u16*)(ws + 25690112);       // 6,422,528 B
    u16*   vb  = (u16*)(ws + 32112640);       // 6,422,528 B
    u16*   bsh = (u16*)(ws + 38535168);       // 393,216 B
    u16*   bsl = (u16*)(ws + 38928384);       // 393,216 B
    u16*   boh = (u16*)(ws + 39321600);       // 131,072 B
    u16*   bol = (u16*)(ws + 39452672);       // 131,072 B
    // xh/xl dead after qkv_mfma; attn reuses them as split-bf16 output
    u16* aoh = xh;
    u16* aol = xl;

    convert_kernel<<<3392, 256, 0, stream>>>(x, wq, wk, wv, wo, xh, xl, bsh, bsl, boh, bol);
    qkv_mfma<<<dim3(6, 98), 256, 0, stream>>>(xh, xl, bsh, bsl, bq, bk, bv, qf, kb, vb);
    attn_kernel<<<dim3(7, 7, 16), 128, 0, stream>>>(qf, kb, vb, aoh, aol);
    out_mfma<<<dim3(2, 196), 256, 0, stream>>>(aoh, aol, boh, bol, bo, out);
}

// Round 5
// 197.310 us; speedup vs baseline: 2.2620x; 1.1320x over previous
//
#include <hip/hip_runtime.h>

typedef unsigned int u32;
typedef unsigned short u16;
typedef __attribute__((ext_vector_type(8))) short bf16x8;
typedef __attribute__((ext_vector_type(4))) float f32x4;

#define T_TOK 12544   // 4*56*56
#define EMB   256
#define IMG   56
#define SCALE 0.17677669529663689f

__device__ __forceinline__ u32 bf16_rtne(float f) {
    u32 u = __builtin_bit_cast(u32, f);
    return (u + 0x7fffu + ((u >> 16) & 1u)) >> 16;
}
__device__ __forceinline__ float bf16_to_f(u32 h) { return __builtin_bit_cast(float, h << 16); }
__device__ __forceinline__ float bf_lo(u32 u) { return __builtin_bit_cast(float, u << 16); }
__device__ __forceinline__ float bf_hi(u32 u) { return __builtin_bit_cast(float, u & 0xffff0000u); }

// async global->LDS, 16B/lane; LDS dest must be wave-uniform base + lane*16
#define GLD16(g, l) __builtin_amdgcn_global_load_lds( \
    (const __attribute__((address_space(1))) u32*)(g), \
    (__attribute__((address_space(3))) u32*)(l), 16, 0, 0)

// ---------------------------------------------------------------------------
// Split fp32 -> bf16 hi/lo pairs: x and the 4 weight matrices.
// qkv weights stacked [768][256] (wq 0-255, wk 256-511, wv 512-767).
// ---------------------------------------------------------------------------
__global__ __launch_bounds__(256) void convert_kernel(
    const float* __restrict__ x, const float* __restrict__ wq, const float* __restrict__ wk,
    const float* __restrict__ wv, const float* __restrict__ wo,
    u16* __restrict__ xh, u16* __restrict__ xl,
    u16* __restrict__ bsh, u16* __restrict__ bsl,
    u16* __restrict__ boh, u16* __restrict__ bol) {
    const int i = blockIdx.x * 256 + threadIdx.x;
    const int NX4 = T_TOK * EMB / 4;
    float4 f;
    u16 *dh, *dl;
    int di;
    if (i < NX4) {
        f = ((const float4*)x)[i];
        dh = xh; dl = xl; di = i;
    } else {
        const int j = i - NX4;
        const int w = j >> 14, widx = j & 16383;
        const float* src = (w == 0) ? wq : (w == 1) ? wk : (w == 2) ? wv : wo;
        f = ((const float4*)src)[widx];
        if (w < 3) { dh = bsh; dl = bsl; di = (w << 14) + widx; }
        else       { dh = boh; dl = bol; di = widx; }
    }
    const float vf[4] = {f.x, f.y, f.z, f.w};
    ushort4 hv, lv;
    u16* hp = (u16*)&hv; u16* lp = (u16*)&lv;
    #pragma unroll
    for (int c = 0; c < 4; ++c) {
        const u32 h = bf16_rtne(vf[c]);
        hp[c] = (u16)h;
        lp[c] = (u16)bf16_rtne(vf[c] - bf16_to_f(h));
    }
    ((ushort4*)dh)[di] = hv;
    ((ushort4*)dl)[di] = lv;
}

// ---------------------------------------------------------------------------
// QKV GEMM, 128x128 tile, pass-inner split-bf16 (3 MFMA passes per k-tile).
// ---------------------------------------------------------------------------
__global__ __launch_bounds__(256) void qkv_mfma(
    const u16* __restrict__ xh, const u16* __restrict__ xl,
    const u16* __restrict__ bsh, const u16* __restrict__ bsl,
    const float* __restrict__ bq, const float* __restrict__ bk, const float* __restrict__ bv,
    float* __restrict__ qf, u16* __restrict__ kb, u16* __restrict__ vb) {
    __shared__ __attribute__((aligned(16))) u16 sAh[128 * 32];
    __shared__ __attribute__((aligned(16))) u16 sAl[128 * 32];
    __shared__ __attribute__((aligned(16))) u16 sBh[128 * 32];
    __shared__ __attribute__((aligned(16))) u16 sBl[128 * 32];
    const int nBase = blockIdx.x * 128;
    const int mBase = blockIdx.y * 128;
    const int tid = threadIdx.x, wv = tid >> 6, ln = tid & 63;
    const int lrow = ln & 15, lqd = ln >> 4;
    const int wm = (wv & 1) * 64, wn = (wv >> 1) * 64;
    const int c0 = wv * 128 + ln, r0 = c0 >> 2, kc0 = c0 & 3;
    const int c1 = c0 + 64,       r1 = c1 >> 2, kc1 = c1 & 3;
    const size_t gA0 = (size_t)(mBase + r0) * EMB + kc0 * 8;
    const size_t gA1 = (size_t)(mBase + r1) * EMB + kc1 * 8;
    const size_t gB0 = (size_t)(nBase + r0) * EMB + kc0 * 8;
    const size_t gB1 = (size_t)(nBase + r1) * EMB + kc1 * 8;
    const int l0 = (wv * 128) * 8, l1 = (wv * 128 + 64) * 8;

    f32x4 acc[4][4];
    #pragma unroll
    for (int mi = 0; mi < 4; ++mi)
        #pragma unroll
        for (int ni = 0; ni < 4; ++ni)
            acc[mi][ni] = (f32x4){0.f, 0.f, 0.f, 0.f};

    for (int kt = 0; kt < 8; ++kt) {
        const int k0 = kt * 32;
        GLD16(xh  + gA0 + k0, sAh + l0);
        GLD16(xh  + gA1 + k0, sAh + l1);
        GLD16(xl  + gA0 + k0, sAl + l0);
        GLD16(xl  + gA1 + k0, sAl + l1);
        GLD16(bsh + gB0 + k0, sBh + l0);
        GLD16(bsh + gB1 + k0, sBh + l1);
        GLD16(bsl + gB0 + k0, sBl + l0);
        GLD16(bsl + gB1 + k0, sBl + l1);
        __syncthreads();
        bf16x8 ah[4], al[4], bh[4], bl[4];
        #pragma unroll
        for (int mi = 0; mi < 4; ++mi) {
            ah[mi] = *(const bf16x8*)&sAh[(wm + mi * 16 + lrow) * 32 + lqd * 8];
            al[mi] = *(const bf16x8*)&sAl[(wm + mi * 16 + lrow) * 32 + lqd * 8];
        }
        #pragma unroll
        for (int ni = 0; ni < 4; ++ni) {
            bh[ni] = *(const bf16x8*)&sBh[(wn + ni * 16 + lrow) * 32 + lqd * 8];
            bl[ni] = *(const bf16x8*)&sBl[(wn + ni * 16 + lrow) * 32 + lqd * 8];
        }
        #pragma unroll
        for (int mi = 0; mi < 4; ++mi)
            #pragma unroll
            for (int ni = 0; ni < 4; ++ni) {
                acc[mi][ni] = __builtin_amdgcn_mfma_f32_16x16x32_bf16(ah[mi], bh[ni], acc[mi][ni], 0, 0, 0);
                acc[mi][ni] = __builtin_amdgcn_mfma_f32_16x16x32_bf16(al[mi], bh[ni], acc[mi][ni], 0, 0, 0);
                acc[mi][ni] = __builtin_amdgcn_mfma_f32_16x16x32_bf16(ah[mi], bl[ni], acc[mi][ni], 0, 0, 0);
            }
        __syncthreads();
    }

    const int which = nBase >> 8;   // 0=q, 1=k, 2=v (uniform)
    const float* bias = (which == 0) ? bq : (which == 1) ? bk : bv;
    #pragma unroll
    for (int ni = 0; ni < 4; ++ni) {
        const int ncol = nBase + wn + ni * 16 + lrow;
        const int c = ncol & 255;
        const float bz = bias[c];
        #pragma unroll
        for (int mi = 0; mi < 4; ++mi) {
            #pragma unroll
            for (int r = 0; r < 4; ++r) {
                const int row = mBase + wm + mi * 16 + lqd * 4 + r;
                const float val = acc[mi][ni][r] + bz;
                if (which == 0)      qf[(size_t)row * EMB + c] = val;
                else if (which == 1) kb[(size_t)row * EMB + c] = (u16)bf16_rtne(val);
                else                 vb[(size_t)row * EMB + c] = (u16)bf16_rtne(val);
            }
        }
    }
}

// ---------------------------------------------------------------------------
// Out-projection, 64x128 tile (grid (2,196) = 392 blocks).
// ---------------------------------------------------------------------------
__global__ __launch_bounds__(256) void out_mfma(
    const u16* __restrict__ aoh, const u16* __restrict__ aol,
    const u16* __restrict__ boh, const u16* __restrict__ bol,
    const float* __restrict__ bo, float* __restrict__ out) {
    __shared__ __attribute__((aligned(16))) u16 sAh[64 * 32];
    __shared__ __attribute__((aligned(16))) u16 sAl[64 * 32];
    __shared__ __attribute__((aligned(16))) u16 sBh[128 * 32];
    __shared__ __attribute__((aligned(16))) u16 sBl[128 * 32];
    const int nBase = blockIdx.x * 128;
    const int mBase = blockIdx.y * 64;
    const int tid = threadIdx.x, wv = tid >> 6, ln = tid & 63;
    const int lrow = ln & 15, lqd = ln >> 4;
    const int cA = wv * 64 + ln, rA = cA >> 2, kcA = cA & 3;
    const size_t gA = (size_t)(mBase + rA) * EMB + kcA * 8;
    const int lA = (wv * 64) * 8;
    const int c0 = wv * 128 + ln, r0 = c0 >> 2, kc0 = c0 & 3;
    const int c1 = c0 + 64,       r1 = c1 >> 2, kc1 = c1 & 3;
    const size_t gB0 = (size_t)(nBase + r0) * EMB + kc0 * 8;
    const size_t gB1 = (size_t)(nBase + r1) * EMB + kc1 * 8;
    const int l0 = (wv * 128) * 8, l1 = (wv * 128 + 64) * 8;

    f32x4 acc[4][2];
    #pragma unroll
    for (int mi = 0; mi < 4; ++mi)
        #pragma unroll
        for (int ni = 0; ni < 2; ++ni)
            acc[mi][ni] = (f32x4){0.f, 0.f, 0.f, 0.f};

    for (int kt = 0; kt < 8; ++kt) {
        const int k0 = kt * 32;
        GLD16(aoh + gA + k0, sAh + lA);
        GLD16(aol + gA + k0, sAl + lA);
        GLD16(boh + gB0 + k0, sBh + l0);
        GLD16(boh + gB1 + k0, sBh + l1);
        GLD16(bol + gB0 + k0, sBl + l0);
        GLD16(bol + gB1 + k0, sBl + l1);
        __syncthreads();
        bf16x8 ah[4], al[4], bh[2], bl[2];
        #pragma unroll
        for (int mi = 0; mi < 4; ++mi) {
            ah[mi] = *(const bf16x8*)&sAh[(mi * 16 + lrow) * 32 + lqd * 8];
            al[mi] = *(const bf16x8*)&sAl[(mi * 16 + lrow) * 32 + lqd * 8];
        }
        #pragma unroll
        for (int ni = 0; ni < 2; ++ni) {
            bh[ni] = *(const bf16x8*)&sBh[(wv * 32 + ni * 16 + lrow) * 32 + lqd * 8];
            bl[ni] = *(const bf16x8*)&sBl[(wv * 32 + ni * 16 + lrow) * 32 + lqd * 8];
        }
        #pragma unroll
        for (int mi = 0; mi < 4; ++mi)
            #pragma unroll
            for (int ni = 0; ni < 2; ++ni) {
                acc[mi][ni] = __builtin_amdgcn_mfma_f32_16x16x32_bf16(ah[mi], bh[ni], acc[mi][ni], 0, 0, 0);
                acc[mi][ni] = __builtin_amdgcn_mfma_f32_16x16x32_bf16(al[mi], bh[ni], acc[mi][ni], 0, 0, 0);
                acc[mi][ni] = __builtin_amdgcn_mfma_f32_16x16x32_bf16(ah[mi], bl[ni], acc[mi][ni], 0, 0, 0);
            }
        __syncthreads();
    }

    #pragma unroll
    for (int ni = 0; ni < 2; ++ni) {
        const int ncol = nBase + wv * 32 + ni * 16 + lrow;
        const float bz = bo[ncol];
        #pragma unroll
        for (int mi = 0; mi < 4; ++mi) {
            #pragma unroll
            for (int r = 0; r < 4; ++r) {
                const int row = mBase + mi * 16 + lqd * 4 + r;
                out[(size_t)row * EMB + ncol] = acc[mi][ni][r] + bz;
            }
        }
    }
}

// ---------------------------------------------------------------------------
// Attention v5: block = 128 thr (2 waves), 8x8 pixel tile, ONE head.
// Neighbor split across waves: wave0 -> j 0..23, wave1 -> j 24..48.
// K and V staged once in pair-major LDS [8 rows][196 p][2 u32] per matrix
// (25 KB); reads are ds_read_b64 with one vaddr + compile-time immediates.
// __launch_bounds__(128,4) hard-caps VGPR at 128 (r3/r4 ballooned to 256
// and spilled ~200 MB to scratch without it).
// Cross-wave softmax: (m,s) exchanged via 1 KB LDS; o combined through the
// dead K region (stride 33 -> conflict-free). OOB halo zero-filled => logit
// exactly 0 (F.unfold zero-padding semantics).
// ---------------------------------------------------------------------------
template<int J0, int NJ>
__device__ __forceinline__ void qk_half(float* __restrict__ lg, const float* __restrict__ qr,
                                        const u32* __restrict__ kv, int pbase2) {
    #pragma unroll
    for (int jj = 0; jj < NJ; ++jj) {
        const int j = J0 + jj;
        const int off2 = 2 * ((j / 7) * 14 + (j % 7));
        float a0 = 0.f, a1 = 0.f;
        #pragma unroll
        for (int f = 0; f < 8; ++f) {
            const uint2 u = *(const uint2*)&kv[f * 392 + pbase2 + off2];
            a0 += qr[4*f]   * bf_lo(u.x); a1 += qr[4*f+1] * bf_hi(u.x);
            a0 += qr[4*f+2] * bf_lo(u.y); a1 += qr[4*f+3] * bf_hi(u.y);
        }
        lg[jj] = (a0 + a1) * SCALE;
    }
}

template<int J0, int NJ>
__device__ __forceinline__ void pv_half(float* __restrict__ o, const float* __restrict__ w,
                                        const u32* __restrict__ kv, int pbase2) {
    #pragma unroll
    for (int jj = 0; jj < NJ; ++jj) {
        const int j = J0 + jj;
        const int off2 = 2 * ((j / 7) * 14 + (j % 7));
        const float wgt = w[jj];
        #pragma unroll
        for (int f = 0; f < 8; ++f) {
            const uint2 u = *(const uint2*)&kv[f * 392 + pbase2 + off2];
            o[4*f]   += wgt * bf_lo(u.x); o[4*f+1] += wgt * bf_hi(u.x);
            o[4*f+2] += wgt * bf_lo(u.y); o[4*f+3] += wgt * bf_hi(u.y);
        }
    }
}

__global__ __launch_bounds__(128, 4) void attn_kernel(
    const float* __restrict__ qf, const u16* __restrict__ kb, const u16* __restrict__ vb,
    u16* __restrict__ aoh, u16* __restrict__ aol) {
    __shared__ __attribute__((aligned(16))) u32 smem[6528];   // 26112 B
    u32* sK = smem;               // [8][392]  (12.5 KB)
    u32* sV = smem + 3136;        // [8][392]  (12.5 KB)
    float* ex = (float*)(smem + 6272);   // [2][64] float2 (1 KB)
    float* sO = (float*)smem;     // overlay on sK (dead after QK), [64][33]

    const int tid = threadIdx.x;
    const int hl = tid >> 6, ln = tid & 63;
    const int img = blockIdx.z >> 3, head = blockIdx.z & 7;
    const int ty0 = blockIdx.y * 8, tx0 = blockIdx.x * 8;

    // ---- stage K and V (1568 uint4-chunks: 196 p x 4 c x {K,V}) ----
    for (int i = tid; i < 1568; i += 128) {
        const int mv = (i >= 784) ? 1 : 0;
        const int ii = i - 784 * mv;
        const int c = ii & 3, p = ii >> 2;
        const int pyh = p / 14, pxh = p - pyh * 14;
        const int gy = ty0 - 3 + pyh, gx = tx0 - 3 + pxh;
        u32* dst = (mv ? sV : sK) + 784 * c + 2 * p;
        if ((unsigned)gy < 56u && (unsigned)gx < 56u) {
            const size_t tt = ((size_t)img * IMG + gy) * IMG + gx;
            const u16* src = (mv ? vb : kb) + tt * EMB + head * 32 + c * 8;
            const uint4 u = *(const uint4*)src;
            *(uint2*)dst         = (uint2){u.x, u.y};
            *(uint2*)(dst + 392) = (uint2){u.z, u.w};
        } else {
            *(uint2*)dst         = (uint2){0u, 0u};
            *(uint2*)(dst + 392) = (uint2){0u, 0u};
        }
    }

    const int py = ln >> 3, px = ln & 7;
    const size_t t = ((size_t)img * IMG + ty0 + py) * IMG + tx0 + px;

    float qr[32];
    const float4* qs = (const float4*)&qf[t * EMB + head * 32];
    #pragma unroll
    for (int i = 0; i < 8; ++i) {
        const float4 f = qs[i];
        qr[4*i] = f.x; qr[4*i+1] = f.y; qr[4*i+2] = f.z; qr[4*i+3] = f.w;
    }
    __syncthreads();

    const int pbase2 = 2 * (py * 14 + px);

    float lg[25];
    if (hl == 0) { qk_half<0, 24>(lg, qr, sK, pbase2); lg[24] = -1e30f; }
    else         { qk_half<24, 25>(lg, qr, sK, pbase2); }

    // local softmax stats
    float ml = lg[0];
    #pragma unroll
    for (int j = 1; j < 25; ++j) ml = fmaxf(ml, lg[j]);
    float sl = 0.f;
    #pragma unroll
    for (int j = 0; j < 25; ++j) { lg[j] = __expf(lg[j] - ml); sl += lg[j]; }

    // cross-wave combine of (m, s)
    ((float2*)ex)[hl * 64 + ln] = (float2){ml, sl};
    __syncthreads();
    const float2 pr = ((float2*)ex)[(1 - hl) * 64 + ln];
    const float m = fmaxf(ml, pr.x);
    const float s = sl * __expf(ml - m) + pr.y * __expf(pr.x - m);
    const float scale = __expf(ml - m) / s;

    float o[32] = {};
    if (hl == 0) pv_half<0, 24>(o, lg, sV, pbase2);
    else         pv_half<24, 25>(o, lg, sV, pbase2);
    #pragma unroll
    for (int d = 0; d < 32; ++d) o[d] *= scale;

    // combine the two waves' partial o through LDS (sK region is dead)
    if (hl == 1) {
        #pragma unroll
        for (int d = 0; d < 32; ++d) sO[ln * 33 + d] = o[d];
    }
    __syncthreads();
    if (hl == 0) {
        #pragma unroll
        for (int d = 0; d < 32; ++d) o[d] += sO[ln * 33 + d];

        u16* ohp = &aoh[t * EMB + head * 32];
        u16* olp = &aol[t * EMB + head * 32];
        #pragma unroll
        for (int g = 0; g < 8; ++g) {
            ushort4 hv, lv;
            u16* hp = (u16*)&hv; u16* lp = (u16*)&lv;
            #pragma unroll
            for (int c = 0; c < 4; ++c) {
                const float v = o[g * 4 + c];
                const u32 h = bf16_rtne(v);
                hp[c] = (u16)h;
                lp[c] = (u16)bf16_rtne(v - bf16_to_f(h));
            }
            ((ushort4*)ohp)[g] = hv;
            ((ushort4*)olp)[g] = lv;
        }
    }
}

extern "C" void kernel_launch(void* const* d_in, const int* in_sizes, int n_in,
                              void* d_out, int out_size, void* d_ws, size_t ws_size,
                              hipStream_t stream) {
    const float* x  = (const float*)d_in[0];
    const float* wq = (const float*)d_in[1];
    const float* wk = (const float*)d_in[2];
    const float* wv = (const float*)d_in[3];
    const float* wo = (const float*)d_in[4];
    const float* bq = (const float*)d_in[5];
    const float* bk = (const float*)d_in[6];
    const float* bv = (const float*)d_in[7];
    const float* bo = (const float*)d_in[8];
    float* out = (float*)d_out;

    char* ws = (char*)d_ws;
    u16*   xh  = (u16*)(ws);                  // 6,422,528 B
    u16*   xl  = (u16*)(ws + 6422528);        // 6,422,528 B
    float* qf  = (float*)(ws + 12845056);     // 12,845,056 B
    u16*   kb  = (u16*)(ws + 25690112);       // 6,422,528 B
    u16*   vb  = (u16*)(ws + 32112640);       // 6,422,528 B
    u16*   bsh = (u16*)(ws + 38535168);       // 393,216 B
    u16*   bsl = (u16*)(ws + 38928384);       // 393,216 B
    u16*   boh = (u16*)(ws + 39321600);       // 131,072 B
    u16*   bol = (u16*)(ws + 39452672);       // 131,072 B
    // xh/xl dead after qkv_mfma; attn reuses them as split-bf16 output
    u16* aoh = xh;
    u16* aol = xl;

    convert_kernel<<<3392, 256, 0, stream>>>(x, wq, wk, wv, wo, xh, xl, bsh, bsl, boh, bol);
    qkv_mfma<<<dim3(6, 98), 256, 0, stream>>>(xh, xl, bsh, bsl, bq, bk, bv, qf, kb, vb);
    attn_kernel<<<dim3(7, 7, 32), 128, 0, stream>>>(qf, kb, vb, aoh, aol);
    out_mfma<<<dim3(2, 196), 256, 0, stream>>>(aoh, aol, boh, bol, bo, out);
}

// Round 6
// 148.960 us; speedup vs baseline: 2.9963x; 1.3246x over previous
//
#include <hip/hip_runtime.h>

typedef unsigned int u32;
typedef unsigned short u16;
typedef __attribute__((ext_vector_type(8))) short bf16x8;
typedef __attribute__((ext_vector_type(4))) float f32x4;

#define T_TOK 12544   // 4*56*56
#define EMB   256
#define IMG   56
#define SCALE 0.17677669529663689f
#define HALO  196
#define KSTR  40      // sK/sV1 row stride (u16): 80B rows -> b128-aligned, bank-uniform frags
#define VTSTR 224     // sVT row stride (u16)
#define PSTR  232     // sP row stride (u16): 464B rows -> b128-aligned, 8-lane/bank-quad frags

__device__ __forceinline__ u32 bf16_rtne(float f) {
    u32 u = __builtin_bit_cast(u32, f);
    return (u + 0x7fffu + ((u >> 16) & 1u)) >> 16;
}
__device__ __forceinline__ float bf16_to_f(u32 h) { return __builtin_bit_cast(float, h << 16); }

// async global->LDS, 16B/lane; LDS dest must be wave-uniform base + lane*16
#define GLD16(g, l) __builtin_amdgcn_global_load_lds( \
    (const __attribute__((address_space(1))) u32*)(g), \
    (__attribute__((address_space(3))) u32*)(l), 16, 0, 0)

// ---------------------------------------------------------------------------
// Split fp32 -> bf16 hi/lo pairs: x and the 4 weight matrices.
// qkv weights stacked [768][256] (wq 0-255, wk 256-511, wv 512-767).
// ---------------------------------------------------------------------------
__global__ __launch_bounds__(256) void convert_kernel(
    const float* __restrict__ x, const float* __restrict__ wq, const float* __restrict__ wk,
    const float* __restrict__ wv, const float* __restrict__ wo,
    u16* __restrict__ xh, u16* __restrict__ xl,
    u16* __restrict__ bsh, u16* __restrict__ bsl,
    u16* __restrict__ boh, u16* __restrict__ bol) {
    const int i = blockIdx.x * 256 + threadIdx.x;
    const int NX4 = T_TOK * EMB / 4;
    float4 f;
    u16 *dh, *dl;
    int di;
    if (i < NX4) {
        f = ((const float4*)x)[i];
        dh = xh; dl = xl; di = i;
    } else {
        const int j = i - NX4;
        const int w = j >> 14, widx = j & 16383;
        const float* src = (w == 0) ? wq : (w == 1) ? wk : (w == 2) ? wv : wo;
        f = ((const float4*)src)[widx];
        if (w < 3) { dh = bsh; dl = bsl; di = (w << 14) + widx; }
        else       { dh = boh; dl = bol; di = widx; }
    }
    const float vf[4] = {f.x, f.y, f.z, f.w};
    ushort4 hv, lv;
    u16* hp = (u16*)&hv; u16* lp = (u16*)&lv;
    #pragma unroll
    for (int c = 0; c < 4; ++c) {
        const u32 h = bf16_rtne(vf[c]);
        hp[c] = (u16)h;
        lp[c] = (u16)bf16_rtne(vf[c] - bf16_to_f(h));
    }
    ((ushort4*)dh)[di] = hv;
    ((ushort4*)dl)[di] = lv;
}

// ---------------------------------------------------------------------------
// QKV GEMM, 128x128 tile, pass-inner split-bf16 (3 MFMA passes per k-tile).
// All outputs bf16: qb, kb, vb [T][256].
// ---------------------------------------------------------------------------
__global__ __launch_bounds__(256) void qkv_mfma(
    const u16* __restrict__ xh, const u16* __restrict__ xl,
    const u16* __restrict__ bsh, const u16* __restrict__ bsl,
    const float* __restrict__ bq, const float* __restrict__ bk, const float* __restrict__ bv,
    u16* __restrict__ qb, u16* __restrict__ kb, u16* __restrict__ vb) {
    __shared__ __attribute__((aligned(16))) u16 sAh[128 * 32];
    __shared__ __attribute__((aligned(16))) u16 sAl[128 * 32];
    __shared__ __attribute__((aligned(16))) u16 sBh[128 * 32];
    __shared__ __attribute__((aligned(16))) u16 sBl[128 * 32];
    const int nBase = blockIdx.x * 128;
    const int mBase = blockIdx.y * 128;
    const int tid = threadIdx.x, wv = tid >> 6, ln = tid & 63;
    const int lrow = ln & 15, lqd = ln >> 4;
    const int wm = (wv & 1) * 64, wn = (wv >> 1) * 64;
    const int c0 = wv * 128 + ln, r0 = c0 >> 2, kc0 = c0 & 3;
    const int c1 = c0 + 64,       r1 = c1 >> 2, kc1 = c1 & 3;
    const size_t gA0 = (size_t)(mBase + r0) * EMB + kc0 * 8;
    const size_t gA1 = (size_t)(mBase + r1) * EMB + kc1 * 8;
    const size_t gB0 = (size_t)(nBase + r0) * EMB + kc0 * 8;
    const size_t gB1 = (size_t)(nBase + r1) * EMB + kc1 * 8;
    const int l0 = (wv * 128) * 8, l1 = (wv * 128 + 64) * 8;

    f32x4 acc[4][4];
    #pragma unroll
    for (int mi = 0; mi < 4; ++mi)
        #pragma unroll
        for (int ni = 0; ni < 4; ++ni)
            acc[mi][ni] = (f32x4){0.f, 0.f, 0.f, 0.f};

    for (int kt = 0; kt < 8; ++kt) {
        const int k0 = kt * 32;
        GLD16(xh  + gA0 + k0, sAh + l0);
        GLD16(xh  + gA1 + k0, sAh + l1);
        GLD16(xl  + gA0 + k0, sAl + l0);
        GLD16(xl  + gA1 + k0, sAl + l1);
        GLD16(bsh + gB0 + k0, sBh + l0);
        GLD16(bsh + gB1 + k0, sBh + l1);
        GLD16(bsl + gB0 + k0, sBl + l0);
        GLD16(bsl + gB1 + k0, sBl + l1);
        __syncthreads();
        bf16x8 ah[4], al[4], bh[4], bl[4];
        #pragma unroll
        for (int mi = 0; mi < 4; ++mi) {
            ah[mi] = *(const bf16x8*)&sAh[(wm + mi * 16 + lrow) * 32 + lqd * 8];
            al[mi] = *(const bf16x8*)&sAl[(wm + mi * 16 + lrow) * 32 + lqd * 8];
        }
        #pragma unroll
        for (int ni = 0; ni < 4; ++ni) {
            bh[ni] = *(const bf16x8*)&sBh[(wn + ni * 16 + lrow) * 32 + lqd * 8];
            bl[ni] = *(const bf16x8*)&sBl[(wn + ni * 16 + lrow) * 32 + lqd * 8];
        }
        #pragma unroll
        for (int mi = 0; mi < 4; ++mi)
            #pragma unroll
            for (int ni = 0; ni < 4; ++ni) {
                acc[mi][ni] = __builtin_amdgcn_mfma_f32_16x16x32_bf16(ah[mi], bh[ni], acc[mi][ni], 0, 0, 0);
                acc[mi][ni] = __builtin_amdgcn_mfma_f32_16x16x32_bf16(al[mi], bh[ni], acc[mi][ni], 0, 0, 0);
                acc[mi][ni] = __builtin_amdgcn_mfma_f32_16x16x32_bf16(ah[mi], bl[ni], acc[mi][ni], 0, 0, 0);
            }
        __syncthreads();
    }

    const int which = nBase >> 8;   // 0=q, 1=k, 2=v (uniform)
    const float* bias = (which == 0) ? bq : (which == 1) ? bk : bv;
    u16* dst = (which == 0) ? qb : (which == 1) ? kb : vb;
    #pragma unroll
    for (int ni = 0; ni < 4; ++ni) {
        const int ncol = nBase + wn + ni * 16 + lrow;
        const int c = ncol & 255;
        const float bz = bias[c];
        #pragma unroll
        for (int mi = 0; mi < 4; ++mi) {
            #pragma unroll
            for (int r = 0; r < 4; ++r) {
                const int row = mBase + wm + mi * 16 + lqd * 4 + r;
                dst[(size_t)row * EMB + c] = (u16)bf16_rtne(acc[mi][ni][r] + bz);
            }
        }
    }
}

// ---------------------------------------------------------------------------
// Out-projection, 64x128 tile (grid (2,196) = 392 blocks).
// ---------------------------------------------------------------------------
__global__ __launch_bounds__(256) void out_mfma(
    const u16* __restrict__ aoh, const u16* __restrict__ aol,
    const u16* __restrict__ boh, const u16* __restrict__ bol,
    const float* __restrict__ bo, float* __restrict__ out) {
    __shared__ __attribute__((aligned(16))) u16 sAh[64 * 32];
    __shared__ __attribute__((aligned(16))) u16 sAl[64 * 32];
    __shared__ __attribute__((aligned(16))) u16 sBh[128 * 32];
    __shared__ __attribute__((aligned(16))) u16 sBl[128 * 32];
    const int nBase = blockIdx.x * 128;
    const int mBase = blockIdx.y * 64;
    const int tid = threadIdx.x, wv = tid >> 6, ln = tid & 63;
    const int lrow = ln & 15, lqd = ln >> 4;
    const int cA = wv * 64 + ln, rA = cA >> 2, kcA = cA & 3;
    const size_t gA = (size_t)(mBase + rA) * EMB + kcA * 8;
    const int lA = (wv * 64) * 8;
    const int c0 = wv * 128 + ln, r0 = c0 >> 2, kc0 = c0 & 3;
    const int c1 = c0 + 64,       r1 = c1 >> 2, kc1 = c1 & 3;
    const size_t gB0 = (size_t)(nBase + r0) * EMB + kc0 * 8;
    const size_t gB1 = (size_t)(nBase + r1) * EMB + kc1 * 8;
    const int l0 = (wv * 128) * 8, l1 = (wv * 128 + 64) * 8;

    f32x4 acc[4][2];
    #pragma unroll
    for (int mi = 0; mi < 4; ++mi)
        #pragma unroll
        for (int ni = 0; ni < 2; ++ni)
            acc[mi][ni] = (f32x4){0.f, 0.f, 0.f, 0.f};

    for (int kt = 0; kt < 8; ++kt) {
        const int k0 = kt * 32;
        GLD16(aoh + gA + k0, sAh + lA);
        GLD16(aol + gA + k0, sAl + lA);
        GLD16(boh + gB0 + k0, sBh + l0);
        GLD16(boh + gB1 + k0, sBh + l1);
        GLD16(bol + gB0 + k0, sBl + l0);
        GLD16(bol + gB1 + k0, sBl + l1);
        __syncthreads();
        bf16x8 ah[4], al[4], bh[2], bl[2];
        #pragma unroll
        for (int mi = 0; mi < 4; ++mi) {
            ah[mi] = *(const bf16x8*)&sAh[(mi * 16 + lrow) * 32 + lqd * 8];
            al[mi] = *(const bf16x8*)&sAl[(mi * 16 + lrow) * 32 + lqd * 8];
        }
        #pragma unroll
        for (int ni = 0; ni < 2; ++ni) {
            bh[ni] = *(const bf16x8*)&sBh[(wv * 32 + ni * 16 + lrow) * 32 + lqd * 8];
            bl[ni] = *(const bf16x8*)&sBl[(wv * 32 + ni * 16 + lrow) * 32 + lqd * 8];
        }
        #pragma unroll
        for (int mi = 0; mi < 4; ++mi)
            #pragma unroll
            for (int ni = 0; ni < 2; ++ni) {
                acc[mi][ni] = __builtin_amdgcn_mfma_f32_16x16x32_bf16(ah[mi], bh[ni], acc[mi][ni], 0, 0, 0);
                acc[mi][ni] = __builtin_amdgcn_mfma_f32_16x16x32_bf16(al[mi], bh[ni], acc[mi][ni], 0, 0, 0);
                acc[mi][ni] = __builtin_amdgcn_mfma_f32_16x16x32_bf16(ah[mi], bl[ni], acc[mi][ni], 0, 0, 0);
            }
        __syncthreads();
    }

    #pragma unroll
    for (int ni = 0; ni < 2; ++ni) {
        const int ncol = nBase + wv * 32 + ni * 16 + lrow;
        const float bz = bo[ncol];
        #pragma unroll
        for (int mi = 0; mi < 4; ++mi) {
            #pragma unroll
            for (int r = 0; r < 4; ++r) {
                const int row = mBase + mi * 16 + lqd * 4 + r;
                out[(size_t)row * EMB + ncol] = acc[mi][ni][r] + bz;
            }
        }
    }
}

// ---------------------------------------------------------------------------
// Attention v6 (MFMA): block = 256 thr = 4 waves = one (img, 8x8 tile, head).
// Wave w owns pixels 16w..16w+15. Dense GEMM over the padded 14x14 halo:
//   QK:  C[16 px][208 halo] = Q[16x32] . K[208x32]^T   (13 mfma)
//   mask out-of-window -> -inf (in-window OOB keeps logit 0: K zero-filled,
//   matching F.unfold zero padding), softmax in C-layout regs,
//   P -> LDS bf16, then
//   PV:  O[16 px][32 d] = P[16x224] . V^T[32x224]^T    (14 mfma)
// LDS strides chosen so all fragment reads are b128 at the 8-cycle minimum.
// ---------------------------------------------------------------------------
__global__ __launch_bounds__(256, 2) void attn_kernel(
    const u16* __restrict__ qb, const u16* __restrict__ kb, const u16* __restrict__ vb,
    u16* __restrict__ aoh, u16* __restrict__ aol) {
    __shared__ __attribute__((aligned(16))) u16 smem[30976];   // 61952 B
    u16* sK  = smem;            // [224][KSTR]  K halo, rows>=196 zero
    u16* sVT = smem + 8960;     // [32][VTSTR]  V^T
    u16* sP  = smem + 16128;    // [4][16][PSTR] P per wave; overlays sV1
    u16* sV1 = sP;              // [224][KSTR]  V halo (dead after transpose)

    const int tid = threadIdx.x;
    const int w = tid >> 6, ln = tid & 63;
    const int lrow = ln & 15, lqd = ln >> 4;
    const int img = blockIdx.z >> 3, head = blockIdx.z & 7;
    const int ty0 = blockIdx.y * 8, tx0 = blockIdx.x * 8;

    // ---- stage K and V halo [p][dim], OOB/pad rows zero ----
    for (int i = tid; i < 1792; i += 256) {
        const int mv = (i >= 896) ? 1 : 0;
        const int ii = i - 896 * mv;
        const int p = ii >> 2, c = ii & 3;
        const int pyh = p / 14, pxh = p - pyh * 14;
        const int gy = ty0 - 3 + pyh, gx = tx0 - 3 + pxh;
        u16* dst = (mv ? sV1 : sK) + p * KSTR + c * 8;
        if (p < HALO && (unsigned)gy < 56u && (unsigned)gx < 56u) {
            const size_t tt = ((size_t)img * IMG + gy) * IMG + gx;
            *(uint4*)dst = *(const uint4*)((mv ? vb : kb) + tt * EMB + head * 32 + c * 8);
        } else {
            *(uint4*)dst = (uint4){0u, 0u, 0u, 0u};
        }
    }
    __syncthreads();

    // ---- transpose V1 [p][d] -> VT [d][p] (zero pad rows carry over) ----
    for (int i = tid; i < 896; i += 256) {
        const int d = i & 31, ho = i >> 5;          // halo octet 8ho..8ho+7
        u32 pk[4];
        #pragma unroll
        for (int j = 0; j < 4; ++j) {
            const u32 a = sV1[(ho * 8 + 2 * j)     * KSTR + d];
            const u32 b = sV1[(ho * 8 + 2 * j + 1) * KSTR + d];
            pk[j] = a | (b << 16);
        }
        *(uint4*)&sVT[d * VTSTR + ho * 8] = *(uint4*)pk;
    }

    // ---- Q A-fragment straight from global (bf16) ----
    const int mpix = w * 16 + lrow;
    const int qpy = mpix >> 3, qpx = mpix & 7;
    const size_t qtok = ((size_t)img * IMG + ty0 + qpy) * IMG + tx0 + qpx;
    const bf16x8 aq = *(const bf16x8*)&qb[qtok * EMB + head * 32 + lqd * 8];

    // ---- QK: 13 N-tiles over halo 0..207 (208..223 fully masked, skipped) ----
    f32x4 ct[13];
    #pragma unroll
    for (int t = 0; t < 13; ++t) ct[t] = (f32x4){0.f, 0.f, 0.f, 0.f};
    #pragma unroll
    for (int t = 0; t < 13; ++t) {
        const bf16x8 bk = *(const bf16x8*)&sK[(t * 16 + lrow) * KSTR + lqd * 8];
        ct[t] = __builtin_amdgcn_mfma_f32_16x16x32_bf16(aq, bk, ct[t], 0, 0, 0);
    }

    // ---- mask + online softmax in C layout (row = lqd*4+r, col = 16t+lrow) ----
    int pys[4], pxs[4];
    #pragma unroll
    for (int r = 0; r < 4; ++r) {
        const int row = lqd * 4 + r;
        pys[r] = 2 * w + (row >> 3);
        pxs[r] = row & 7;
    }
    float mr4[4] = {-1e30f, -1e30f, -1e30f, -1e30f};
    #pragma unroll
    for (int t = 0; t < 13; ++t) {
        const int col = t * 16 + lrow;
        const int hy = col / 14, hx = col - 14 * hy;
        const bool okc = (col < HALO);
        #pragma unroll
        for (int r = 0; r < 4; ++r) {
            const bool ok = ((unsigned)(hy - pys[r]) < 7u) &
                            ((unsigned)(hx - pxs[r]) < 7u) & okc;
            const float lv = ok ? ct[t][r] * SCALE : -1e30f;
            ct[t][r] = lv;
            mr4[r] = fmaxf(mr4[r], lv);
        }
    }
    #pragma unroll
    for (int r = 0; r < 4; ++r) {
        float m = mr4[r];
        m = fmaxf(m, __shfl_xor(m, 1));
        m = fmaxf(m, __shfl_xor(m, 2));
        m = fmaxf(m, __shfl_xor(m, 4));
        m = fmaxf(m, __shfl_xor(m, 8));
        mr4[r] = m;
    }
    float sr4[4] = {0.f, 0.f, 0.f, 0.f};
    #pragma unroll
    for (int t = 0; t < 13; ++t)
        #pragma unroll
        for (int r = 0; r < 4; ++r) {
            const float e = __expf(ct[t][r] - mr4[r]);
            ct[t][r] = e;
            sr4[r] += e;
        }
    #pragma unroll
    for (int r = 0; r < 4; ++r) {
        float s = sr4[r];
        s += __shfl_xor(s, 1);
        s += __shfl_xor(s, 2);
        s += __shfl_xor(s, 4);
        s += __shfl_xor(s, 8);
        sr4[r] = 1.0f / s;
    }

    __syncthreads();   // all transpose reads of sV1 done before P overwrites it

    // ---- P (bf16) to LDS; zero cols 208..223 ----
    u16* sPw = sP + w * 16 * PSTR;
    #pragma unroll
    for (int t = 0; t < 13; ++t)
        #pragma unroll
        for (int r = 0; r < 4; ++r)
            sPw[(lqd * 4 + r) * PSTR + t * 16 + lrow] = (u16)bf16_rtne(ct[t][r]);
    #pragma unroll
    for (int z = 0; z < 4; ++z) {
        const int idx = z * 64 + ln;
        sPw[(idx >> 4) * PSTR + 208 + (idx & 15)] = 0;
    }

    // ---- PV: O[16][32] = P[16x224] . VT[32x224]^T ----
    f32x4 o0 = (f32x4){0.f, 0.f, 0.f, 0.f};
    f32x4 o1 = (f32x4){0.f, 0.f, 0.f, 0.f};
    #pragma unroll
    for (int ks = 0; ks < 7; ++ks) {
        const bf16x8 ap  = *(const bf16x8*)&sPw[lrow * PSTR + ks * 32 + lqd * 8];
        const bf16x8 bv0 = *(const bf16x8*)&sVT[lrow * VTSTR + ks * 32 + lqd * 8];
        const bf16x8 bv1 = *(const bf16x8*)&sVT[(16 + lrow) * VTSTR + ks * 32 + lqd * 8];
        o0 = __builtin_amdgcn_mfma_f32_16x16x32_bf16(ap, bv0, o0, 0, 0, 0);
        o1 = __builtin_amdgcn_mfma_f32_16x16x32_bf16(ap, bv1, o1, 0, 0, 0);
    }

    // ---- epilogue: scale by 1/s, split-bf16, store ----
    #pragma unroll
    for (int r = 0; r < 4; ++r) {
        const int row = lqd * 4 + r;
        const int opy = 2 * w + (row >> 3), opx = row & 7;
        const size_t ot = ((size_t)img * IMG + ty0 + opy) * IMG + tx0 + opx;
        const float inv = sr4[r];
        const float v0 = o0[r] * inv;
        const float v1 = o1[r] * inv;
        const size_t base = ot * EMB + head * 32;
        const u32 h0 = bf16_rtne(v0);
        aoh[base + lrow] = (u16)h0;
        aol[base + lrow] = (u16)bf16_rtne(v0 - bf16_to_f(h0));
        const u32 h1 = bf16_rtne(v1);
        aoh[base + 16 + lrow] = (u16)h1;
        aol[base + 16 + lrow] = (u16)bf16_rtne(v1 - bf16_to_f(h1));
    }
}

extern "C" void kernel_launch(void* const* d_in, const int* in_sizes, int n_in,
                              void* d_out, int out_size, void* d_ws, size_t ws_size,
                              hipStream_t stream) {
    const float* x  = (const float*)d_in[0];
    const float* wq = (const float*)d_in[1];
    const float* wk = (const float*)d_in[2];
    const float* wv = (const float*)d_in[3];
    const float* wo = (const float*)d_in[4];
    const float* bq = (const float*)d_in[5];
    const float* bk = (const float*)d_in[6];
    const float* bv = (const float*)d_in[7];
    const float* bo = (const float*)d_in[8];
    float* out = (float*)d_out;

    char* ws = (char*)d_ws;
    u16*   xh  = (u16*)(ws);                  // 6,422,528 B
    u16*   xl  = (u16*)(ws + 6422528);        // 6,422,528 B
    u16*   qb  = (u16*)(ws + 12845056);       // 6,422,528 B (bf16 now)
    u16*   kb  = (u16*)(ws + 25690112);       // 6,422,528 B
    u16*   vb  = (u16*)(ws + 32112640);       // 6,422,528 B
    u16*   bsh = (u16*)(ws + 38535168);       // 393,216 B
    u16*   bsl = (u16*)(ws + 38928384);       // 393,216 B
    u16*   boh = (u16*)(ws + 39321600);       // 131,072 B
    u16*   bol = (u16*)(ws + 39452672);       // 131,072 B
    // xh/xl dead after qkv_mfma; attn reuses them as split-bf16 output
    u16* aoh = xh;
    u16* aol = xl;

    convert_kernel<<<3392, 256, 0, stream>>>(x, wq, wk, wv, wo, xh, xl, bsh, bsl, boh, bol);
    qkv_mfma<<<dim3(6, 98), 256, 0, stream>>>(xh, xl, bsh, bsl, bq, bk, bv, qb, kb, vb);
    attn_kernel<<<dim3(7, 7, 32), 256, 0, stream>>>(qb, kb, vb, aoh, aol);
    out_mfma<<<dim3(2, 196), 256, 0, stream>>>(aoh, aol, boh, bol, bo, out);
}

// Round 7
// 136.428 us; speedup vs baseline: 3.2715x; 1.0919x over previous
//
#include <hip/hip_runtime.h>

typedef unsigned int u32;
typedef unsigned short u16;
typedef __attribute__((ext_vector_type(8))) short bf16x8;
typedef __attribute__((ext_vector_type(4))) float f32x4;

#define T_TOK 12544   // 4*56*56
#define EMB   256
#define IMG   56
#define SCALE 0.17677669529663689f
#define HALO  196
#define KSTR  40      // sK/sV1 row stride (u16)
#define VTSTR 224     // sVT row stride (u16)
#define PSTR  232     // sP row stride (u16)

__device__ __forceinline__ u32 bf16_rtne(float f) {
    u32 u = __builtin_bit_cast(u32, f);
    return (u + 0x7fffu + ((u >> 16) & 1u)) >> 16;
}
__device__ __forceinline__ float bf16_to_f(u32 h) { return __builtin_bit_cast(float, h << 16); }

// async global->LDS, 16B/lane; LDS dest must be wave-uniform base + lane*16
#define GLD16(g, l) __builtin_amdgcn_global_load_lds( \
    (const __attribute__((address_space(1))) u32*)(g), \
    (__attribute__((address_space(3))) u32*)(l), 16, 0, 0)

// ---------------------------------------------------------------------------
// Convert: x -> bf16 (hi only; qkv GEMM is single-pass now), qkv weights ->
// bf16 stacked [768][256], wo -> split bf16 hi/lo (out GEMM stays 3-pass).
// ---------------------------------------------------------------------------
__global__ __launch_bounds__(256) void convert_kernel(
    const float* __restrict__ x, const float* __restrict__ wq, const float* __restrict__ wk,
    const float* __restrict__ wv, const float* __restrict__ wo,
    u16* __restrict__ xh, u16* __restrict__ bsh,
    u16* __restrict__ boh, u16* __restrict__ bol) {
    const int i = blockIdx.x * 256 + threadIdx.x;
    const int NX4 = T_TOK * EMB / 4;   // 802816
    if (i < NX4) {
        const float4 f = ((const float4*)x)[i];
        const float vf[4] = {f.x, f.y, f.z, f.w};
        ushort4 hv;
        u16* hp = (u16*)&hv;
        #pragma unroll
        for (int c = 0; c < 4; ++c) hp[c] = (u16)bf16_rtne(vf[c]);
        ((ushort4*)xh)[i] = hv;
    } else {
        const int j = i - NX4;                 // < 65536
        const int w = j >> 14, widx = j & 16383;
        const float* src = (w == 0) ? wq : (w == 1) ? wk : (w == 2) ? wv : wo;
        const float4 f = ((const float4*)src)[widx];
        const float vf[4] = {f.x, f.y, f.z, f.w};
        if (w < 3) {
            ushort4 hv;
            u16* hp = (u16*)&hv;
            #pragma unroll
            for (int c = 0; c < 4; ++c) hp[c] = (u16)bf16_rtne(vf[c]);
            ((ushort4*)bsh)[(w << 14) + widx] = hv;
        } else {
            ushort4 hv, lv;
            u16* hp = (u16*)&hv; u16* lp = (u16*)&lv;
            #pragma unroll
            for (int c = 0; c < 4; ++c) {
                const u32 h = bf16_rtne(vf[c]);
                hp[c] = (u16)h;
                lp[c] = (u16)bf16_rtne(vf[c] - bf16_to_f(h));
            }
            ((ushort4*)boh)[widx] = hv;
            ((ushort4*)bol)[widx] = lv;
        }
    }
}

// ---------------------------------------------------------------------------
// QKV GEMM, 128x128 tile, SINGLE-pass bf16 (q/k/v are bf16-rounded on output
// anyway -> 3-pass precision was destroyed by the rounding; single-pass adds
// input-rounding error of the same magnitude). 16 KB LDS, 4 GLD16/thread/kt.
// ---------------------------------------------------------------------------
__global__ __launch_bounds__(256) void qkv_mfma(
    const u16* __restrict__ xh, const u16* __restrict__ bsh,
    const float* __restrict__ bq, const float* __restrict__ bk, const float* __restrict__ bv,
    u16* __restrict__ qb, u16* __restrict__ kb, u16* __restrict__ vb) {
    __shared__ __attribute__((aligned(16))) u16 sA[128 * 32];
    __shared__ __attribute__((aligned(16))) u16 sB[128 * 32];
    const int nBase = blockIdx.x * 128;
    const int mBase = blockIdx.y * 128;
    const int tid = threadIdx.x, wv = tid >> 6, ln = tid & 63;
    const int lrow = ln & 15, lqd = ln >> 4;
    const int wm = (wv & 1) * 64, wn = (wv >> 1) * 64;
    const int c0 = wv * 128 + ln, r0 = c0 >> 2, kc0 = c0 & 3;
    const int c1 = c0 + 64,       r1 = c1 >> 2, kc1 = c1 & 3;
    const size_t gA0 = (size_t)(mBase + r0) * EMB + kc0 * 8;
    const size_t gA1 = (size_t)(mBase + r1) * EMB + kc1 * 8;
    const size_t gB0 = (size_t)(nBase + r0) * EMB + kc0 * 8;
    const size_t gB1 = (size_t)(nBase + r1) * EMB + kc1 * 8;
    const int l0 = (wv * 128) * 8, l1 = (wv * 128 + 64) * 8;

    f32x4 acc[4][4];
    #pragma unroll
    for (int mi = 0; mi < 4; ++mi)
        #pragma unroll
        for (int ni = 0; ni < 4; ++ni)
            acc[mi][ni] = (f32x4){0.f, 0.f, 0.f, 0.f};

    for (int kt = 0; kt < 8; ++kt) {
        const int k0 = kt * 32;
        GLD16(xh  + gA0 + k0, sA + l0);
        GLD16(xh  + gA1 + k0, sA + l1);
        GLD16(bsh + gB0 + k0, sB + l0);
        GLD16(bsh + gB1 + k0, sB + l1);
        __syncthreads();
        bf16x8 af[4], bf[4];
        #pragma unroll
        for (int mi = 0; mi < 4; ++mi)
            af[mi] = *(const bf16x8*)&sA[(wm + mi * 16 + lrow) * 32 + lqd * 8];
        #pragma unroll
        for (int ni = 0; ni < 4; ++ni)
            bf[ni] = *(const bf16x8*)&sB[(wn + ni * 16 + lrow) * 32 + lqd * 8];
        #pragma unroll
        for (int mi = 0; mi < 4; ++mi)
            #pragma unroll
            for (int ni = 0; ni < 4; ++ni)
                acc[mi][ni] = __builtin_amdgcn_mfma_f32_16x16x32_bf16(af[mi], bf[ni], acc[mi][ni], 0, 0, 0);
        __syncthreads();
    }

    const int which = nBase >> 8;   // 0=q, 1=k, 2=v (uniform)
    const float* bias = (which == 0) ? bq : (which == 1) ? bk : bv;
    u16* dst = (which == 0) ? qb : (which == 1) ? kb : vb;
    #pragma unroll
    for (int ni = 0; ni < 4; ++ni) {
        const int ncol = nBase + wn + ni * 16 + lrow;
        const int c = ncol & 255;
        const float bz = bias[c];
        #pragma unroll
        for (int mi = 0; mi < 4; ++mi) {
            #pragma unroll
            for (int r = 0; r < 4; ++r) {
                const int row = mBase + wm + mi * 16 + lqd * 4 + r;
                dst[(size_t)row * EMB + c] = (u16)bf16_rtne(acc[mi][ni][r] + bz);
            }
        }
    }
}

// ---------------------------------------------------------------------------
// Out-projection, 64x128 tile (grid (2,196) = 392 blocks), 3-pass split-bf16
// (output is the fp32 comparand -> keep full precision here).
// ---------------------------------------------------------------------------
__global__ __launch_bounds__(256) void out_mfma(
    const u16* __restrict__ aoh, const u16* __restrict__ aol,
    const u16* __restrict__ boh, const u16* __restrict__ bol,
    const float* __restrict__ bo, float* __restrict__ out) {
    __shared__ __attribute__((aligned(16))) u16 sAh[64 * 32];
    __shared__ __attribute__((aligned(16))) u16 sAl[64 * 32];
    __shared__ __attribute__((aligned(16))) u16 sBh[128 * 32];
    __shared__ __attribute__((aligned(16))) u16 sBl[128 * 32];
    const int nBase = blockIdx.x * 128;
    const int mBase = blockIdx.y * 64;
    const int tid = threadIdx.x, wv = tid >> 6, ln = tid & 63;
    const int lrow = ln & 15, lqd = ln >> 4;
    const int cA = wv * 64 + ln, rA = cA >> 2, kcA = cA & 3;
    const size_t gA = (size_t)(mBase + rA) * EMB + kcA * 8;
    const int lA = (wv * 64) * 8;
    const int c0 = wv * 128 + ln, r0 = c0 >> 2, kc0 = c0 & 3;
    const int c1 = c0 + 64,       r1 = c1 >> 2, kc1 = c1 & 3;
    const size_t gB0 = (size_t)(nBase + r0) * EMB + kc0 * 8;
    const size_t gB1 = (size_t)(nBase + r1) * EMB + kc1 * 8;
    const int l0 = (wv * 128) * 8, l1 = (wv * 128 + 64) * 8;

    f32x4 acc[4][2];
    #pragma unroll
    for (int mi = 0; mi < 4; ++mi)
        #pragma unroll
        for (int ni = 0; ni < 2; ++ni)
            acc[mi][ni] = (f32x4){0.f, 0.f, 0.f, 0.f};

    for (int kt = 0; kt < 8; ++kt) {
        const int k0 = kt * 32;
        GLD16(aoh + gA + k0, sAh + lA);
        GLD16(aol + gA + k0, sAl + lA);
        GLD16(boh + gB0 + k0, sBh + l0);
        GLD16(boh + gB1 + k0, sBh + l1);
        GLD16(bol + gB0 + k0, sBl + l0);
        GLD16(bol + gB1 + k0, sBl + l1);
        __syncthreads();
        bf16x8 ah[4], al[4], bh[2], bl[2];
        #pragma unroll
        for (int mi = 0; mi < 4; ++mi) {
            ah[mi] = *(const bf16x8*)&sAh[(mi * 16 + lrow) * 32 + lqd * 8];
            al[mi] = *(const bf16x8*)&sAl[(mi * 16 + lrow) * 32 + lqd * 8];
        }
        #pragma unroll
        for (int ni = 0; ni < 2; ++ni) {
            bh[ni] = *(const bf16x8*)&sBh[(wv * 32 + ni * 16 + lrow) * 32 + lqd * 8];
            bl[ni] = *(const bf16x8*)&sBl[(wv * 32 + ni * 16 + lrow) * 32 + lqd * 8];
        }
        #pragma unroll
        for (int mi = 0; mi < 4; ++mi)
            #pragma unroll
            for (int ni = 0; ni < 2; ++ni) {
                acc[mi][ni] = __builtin_amdgcn_mfma_f32_16x16x32_bf16(ah[mi], bh[ni], acc[mi][ni], 0, 0, 0);
                acc[mi][ni] = __builtin_amdgcn_mfma_f32_16x16x32_bf16(al[mi], bh[ni], acc[mi][ni], 0, 0, 0);
                acc[mi][ni] = __builtin_amdgcn_mfma_f32_16x16x32_bf16(ah[mi], bl[ni], acc[mi][ni], 0, 0, 0);
            }
        __syncthreads();
    }

    #pragma unroll
    for (int ni = 0; ni < 2; ++ni) {
        const int ncol = nBase + wv * 32 + ni * 16 + lrow;
        const float bz = bo[ncol];
        #pragma unroll
        for (int mi = 0; mi < 4; ++mi) {
            #pragma unroll
            for (int r = 0; r < 4; ++r) {
                const int row = mBase + mi * 16 + lqd * 4 + r;
                out[(size_t)row * EMB + ncol] = acc[mi][ni][r] + bz;
            }
        }
    }
}

// ---------------------------------------------------------------------------
// Attention (MFMA, r6 design unchanged): block = 256 thr = 4 waves = one
// (img, 8x8 tile, head). QK over padded 14x14 halo (13 mfma), mask ->
// -inf, softmax in C-layout regs, P -> LDS bf16, PV (14 mfma).
// ---------------------------------------------------------------------------
__global__ __launch_bounds__(256, 2) void attn_kernel(
    const u16* __restrict__ qb, const u16* __restrict__ kb, const u16* __restrict__ vb,
    u16* __restrict__ aoh, u16* __restrict__ aol) {
    __shared__ __attribute__((aligned(16))) u16 smem[30976];   // 61952 B
    u16* sK  = smem;            // [224][KSTR]  K halo, rows>=196 zero
    u16* sVT = smem + 8960;     // [32][VTSTR]  V^T
    u16* sP  = smem + 16128;    // [4][16][PSTR] P per wave; overlays sV1
    u16* sV1 = sP;              // [224][KSTR]  V halo (dead after transpose)

    const int tid = threadIdx.x;
    const int w = tid >> 6, ln = tid & 63;
    const int lrow = ln & 15, lqd = ln >> 4;
    const int img = blockIdx.z >> 3, head = blockIdx.z & 7;
    const int ty0 = blockIdx.y * 8, tx0 = blockIdx.x * 8;

    // ---- stage K and V halo [p][dim], OOB/pad rows zero ----
    for (int i = tid; i < 1792; i += 256) {
        const int mv = (i >= 896) ? 1 : 0;
        const int ii = i - 896 * mv;
        const int p = ii >> 2, c = ii & 3;
        const int pyh = p / 14, pxh = p - pyh * 14;
        const int gy = ty0 - 3 + pyh, gx = tx0 - 3 + pxh;
        u16* dst = (mv ? sV1 : sK) + p * KSTR + c * 8;
        if (p < HALO && (unsigned)gy < 56u && (unsigned)gx < 56u) {
            const size_t tt = ((size_t)img * IMG + gy) * IMG + gx;
            *(uint4*)dst = *(const uint4*)((mv ? vb : kb) + tt * EMB + head * 32 + c * 8);
        } else {
            *(uint4*)dst = (uint4){0u, 0u, 0u, 0u};
        }
    }
    __syncthreads();

    // ---- transpose V1 [p][d] -> VT [d][p] (zero pad rows carry over) ----
    for (int i = tid; i < 896; i += 256) {
        const int d = i & 31, ho = i >> 5;          // halo octet 8ho..8ho+7
        u32 pk[4];
        #pragma unroll
        for (int j = 0; j < 4; ++j) {
            const u32 a = sV1[(ho * 8 + 2 * j)     * KSTR + d];
            const u32 b = sV1[(ho * 8 + 2 * j + 1) * KSTR + d];
            pk[j] = a | (b << 16);
        }
        *(uint4*)&sVT[d * VTSTR + ho * 8] = *(uint4*)pk;
    }

    // ---- Q A-fragment straight from global (bf16) ----
    const int mpix = w * 16 + lrow;
    const int qpy = mpix >> 3, qpx = mpix & 7;
    const size_t qtok = ((size_t)img * IMG + ty0 + qpy) * IMG + tx0 + qpx;
    const bf16x8 aq = *(const bf16x8*)&qb[qtok * EMB + head * 32 + lqd * 8];

    // ---- QK: 13 N-tiles over halo 0..207 ----
    f32x4 ct[13];
    #pragma unroll
    for (int t = 0; t < 13; ++t) ct[t] = (f32x4){0.f, 0.f, 0.f, 0.f};
    #pragma unroll
    for (int t = 0; t < 13; ++t) {
        const bf16x8 bk = *(const bf16x8*)&sK[(t * 16 + lrow) * KSTR + lqd * 8];
        ct[t] = __builtin_amdgcn_mfma_f32_16x16x32_bf16(aq, bk, ct[t], 0, 0, 0);
    }

    // ---- mask + softmax in C layout (row = lqd*4+r, col = 16t+lrow) ----
    int pys[4], pxs[4];
    #pragma unroll
    for (int r = 0; r < 4; ++r) {
        const int row = lqd * 4 + r;
        pys[r] = 2 * w + (row >> 3);
        pxs[r] = row & 7;
    }
    float mr4[4] = {-1e30f, -1e30f, -1e30f, -1e30f};
    #pragma unroll
    for (int t = 0; t < 13; ++t) {
        const int col = t * 16 + lrow;
        const int hy = col / 14, hx = col - 14 * hy;
        const bool okc = (col < HALO);
        #pragma unroll
        for (int r = 0; r < 4; ++r) {
            const bool ok = ((unsigned)(hy - pys[r]) < 7u) &
                            ((unsigned)(hx - pxs[r]) < 7u) & okc;
            const float lv = ok ? ct[t][r] * SCALE : -1e30f;
            ct[t][r] = lv;
            mr4[r] = fmaxf(mr4[r], lv);
        }
    }
    #pragma unroll
    for (int r = 0; r < 4; ++r) {
        float m = mr4[r];
        m = fmaxf(m, __shfl_xor(m, 1));
        m = fmaxf(m, __shfl_xor(m, 2));
        m = fmaxf(m, __shfl_xor(m, 4));
        m = fmaxf(m, __shfl_xor(m, 8));
        mr4[r] = m;
    }
    float sr4[4] = {0.f, 0.f, 0.f, 0.f};
    #pragma unroll
    for (int t = 0; t < 13; ++t)
        #pragma unroll
        for (int r = 0; r < 4; ++r) {
            const float e = __expf(ct[t][r] - mr4[r]);
            ct[t][r] = e;
            sr4[r] += e;
        }
    #pragma unroll
    for (int r = 0; r < 4; ++r) {
        float s = sr4[r];
        s += __shfl_xor(s, 1);
        s += __shfl_xor(s, 2);
        s += __shfl_xor(s, 4);
        s += __shfl_xor(s, 8);
        sr4[r] = 1.0f / s;
    }

    __syncthreads();   // all transpose reads of sV1 done before P overwrites it

    // ---- P (bf16) to LDS; zero cols 208..223 ----
    u16* sPw = sP + w * 16 * PSTR;
    #pragma unroll
    for (int t = 0; t < 13; ++t)
        #pragma unroll
        for (int r = 0; r < 4; ++r)
            sPw[(lqd * 4 + r) * PSTR + t * 16 + lrow] = (u16)bf16_rtne(ct[t][r]);
    #pragma unroll
    for (int z = 0; z < 4; ++z) {
        const int idx = z * 64 + ln;
        sPw[(idx >> 4) * PSTR + 208 + (idx & 15)] = 0;
    }

    // ---- PV: O[16][32] = P[16x224] . VT[32x224]^T ----
    f32x4 o0 = (f32x4){0.f, 0.f, 0.f, 0.f};
    f32x4 o1 = (f32x4){0.f, 0.f, 0.f, 0.f};
    #pragma unroll
    for (int ks = 0; ks < 7; ++ks) {
        const bf16x8 ap  = *(const bf16x8*)&sPw[lrow * PSTR + ks * 32 + lqd * 8];
        const bf16x8 bv0 = *(const bf16x8*)&sVT[lrow * VTSTR + ks * 32 + lqd * 8];
        const bf16x8 bv1 = *(const bf16x8*)&sVT[(16 + lrow) * VTSTR + ks * 32 + lqd * 8];
        o0 = __builtin_amdgcn_mfma_f32_16x16x32_bf16(ap, bv0, o0, 0, 0, 0);
        o1 = __builtin_amdgcn_mfma_f32_16x16x32_bf16(ap, bv1, o1, 0, 0, 0);
    }

    // ---- epilogue: scale by 1/s, split-bf16, store ----
    #pragma unroll
    for (int r = 0; r < 4; ++r) {
        const int row = lqd * 4 + r;
        const int opy = 2 * w + (row >> 3), opx = row & 7;
        const size_t ot = ((size_t)img * IMG + ty0 + opy) * IMG + tx0 + opx;
        const float inv = sr4[r];
        const float v0 = o0[r] * inv;
        const float v1 = o1[r] * inv;
        const size_t base = ot * EMB + head * 32;
        const u32 h0 = bf16_rtne(v0);
        aoh[base + lrow] = (u16)h0;
        aol[base + lrow] = (u16)bf16_rtne(v0 - bf16_to_f(h0));
        const u32 h1 = bf16_rtne(v1);
        aoh[base + 16 + lrow] = (u16)h1;
        aol[base + 16 + lrow] = (u16)bf16_rtne(v1 - bf16_to_f(h1));
    }
}

extern "C" void kernel_launch(void* const* d_in, const int* in_sizes, int n_in,
                              void* d_out, int out_size, void* d_ws, size_t ws_size,
                              hipStream_t stream) {
    const float* x  = (const float*)d_in[0];
    const float* wq = (const float*)d_in[1];
    const float* wk = (const float*)d_in[2];
    const float* wv = (const float*)d_in[3];
    const float* wo = (const float*)d_in[4];
    const float* bq = (const float*)d_in[5];
    const float* bk = (const float*)d_in[6];
    const float* bv = (const float*)d_in[7];
    const float* bo = (const float*)d_in[8];
    float* out = (float*)d_out;

    char* ws = (char*)d_ws;
    u16* xh  = (u16*)(ws);               // 6,422,528 B  bf16 x
    u16* qb  = (u16*)(ws +  6422528);    // 6,422,528 B
    u16* kb  = (u16*)(ws + 12845056);    // 6,422,528 B
    u16* vb  = (u16*)(ws + 19267584);    // 6,422,528 B
    u16* aoh = (u16*)(ws + 25690112);    // 6,422,528 B
    u16* aol = (u16*)(ws + 32112640);    // 6,422,528 B
    u16* bsh = (u16*)(ws + 38535168);    // 393,216 B  stacked qkv weights bf16
    u16* boh = (u16*)(ws + 38928384);    // 131,072 B  wo hi
    u16* bol = (u16*)(ws + 39059456);    // 131,072 B  wo lo -> total 39,190,528 B

    convert_kernel<<<3392, 256, 0, stream>>>(x, wq, wk, wv, wo, xh, bsh, boh, bol);
    qkv_mfma<<<dim3(6, 98), 256, 0, stream>>>(xh, bsh, bq, bk, bv, qb, kb, vb);
    attn_kernel<<<dim3(7, 7, 32), 256, 0, stream>>>(qb, kb, vb, aoh, aol);
    out_mfma<<<dim3(2, 196), 256, 0, stream>>>(aoh, aol, boh, bol, bo, out);
}

// Round 9
// 133.789 us; speedup vs baseline: 3.3360x; 1.0197x over previous
//
#include <hip/hip_runtime.h>

typedef unsigned int u32;
typedef unsigned short u16;
typedef __attribute__((ext_vector_type(8))) short bf16x8;
typedef __attribute__((ext_vector_type(4))) float f32x4;

#define T_TOK 12544   // 4*56*56
#define EMB   256
#define IMG   56
#define SCALE 0.17677669529663689f
#define HALO  196
#define KSTR  40      // sK/sV1 row stride (u16)
#define VTSTR 224     // sVT row stride (u16)
#define PSTR  232     // sP row stride (u16)

__device__ __forceinline__ u32 bf16_rtne(float f) {
    u32 u = __builtin_bit_cast(u32, f);
    return (u + 0x7fffu + ((u >> 16) & 1u)) >> 16;
}
__device__ __forceinline__ float bf16_to_f(u32 h) { return __builtin_bit_cast(float, h << 16); }
__device__ __forceinline__ u32 pk2(float a, float b) {
    return bf16_rtne(a) | (bf16_rtne(b) << 16);   // RTNE pack, same as v_cvt_pk_bf16_f32
}

// async global->LDS, 16B/lane; LDS dest must be wave-uniform base + lane*16
#define GLD16(g, l) __builtin_amdgcn_global_load_lds( \
    (const __attribute__((address_space(1))) u32*)(g), \
    (__attribute__((address_space(3))) u32*)(l), 16, 0, 0)

// ---------------------------------------------------------------------------
// Weight convert only (x is converted in-flight inside qkv_mfma now):
// qkv weights -> bf16 stacked [768][256]; wo -> split bf16 hi/lo.
// ---------------------------------------------------------------------------
__global__ __launch_bounds__(256) void weight_convert(
    const float* __restrict__ wq, const float* __restrict__ wk,
    const float* __restrict__ wv, const float* __restrict__ wo,
    u16* __restrict__ bsh, u16* __restrict__ boh, u16* __restrict__ bol) {
    const int i = blockIdx.x * 256 + threadIdx.x;   // < 65536
    const int w = i >> 14, widx = i & 16383;
    const float* src = (w == 0) ? wq : (w == 1) ? wk : (w == 2) ? wv : wo;
    const float4 f = ((const float4*)src)[widx];
    const float vf[4] = {f.x, f.y, f.z, f.w};
    if (w < 3) {
        ushort4 hv;
        u16* hp = (u16*)&hv;
        #pragma unroll
        for (int c = 0; c < 4; ++c) hp[c] = (u16)bf16_rtne(vf[c]);
        ((ushort4*)bsh)[(w << 14) + widx] = hv;
    } else {
        ushort4 hv, lv;
        u16* hp = (u16*)&hv; u16* lp = (u16*)&lv;
        #pragma unroll
        for (int c = 0; c < 4; ++c) {
            const u32 h = bf16_rtne(vf[c]);
            hp[c] = (u16)h;
            lp[c] = (u16)bf16_rtne(vf[c] - bf16_to_f(h));
        }
        ((ushort4*)boh)[widx] = hv;
        ((ushort4*)bol)[widx] = lv;
    }
}

// ---------------------------------------------------------------------------
// QKV GEMM, 128x128 tile, single-pass bf16. A staged from fp32 x with
// in-register RTNE pack + ds_write_b128; B via async GLD16.
// ---------------------------------------------------------------------------
__global__ __launch_bounds__(256) void qkv_mfma(
    const float* __restrict__ x, const u16* __restrict__ bsh,
    const float* __restrict__ bq, const float* __restrict__ bk, const float* __restrict__ bv,
    u16* __restrict__ qb, u16* __restrict__ kb, u16* __restrict__ vb) {
    __shared__ __attribute__((aligned(16))) u16 sA[128 * 32];
    __shared__ __attribute__((aligned(16))) u16 sB[128 * 32];
    const int nBase = blockIdx.x * 128;
    const int mBase = blockIdx.y * 128;
    const int tid = threadIdx.x, wv = tid >> 6, ln = tid & 63;
    const int lrow = ln & 15, lqd = ln >> 4;
    const int wm = (wv & 1) * 64, wn = (wv >> 1) * 64;
    const int c0 = wv * 128 + ln, r0 = c0 >> 2, kc0 = c0 & 3;
    const int c1 = c0 + 64,       r1 = c1 >> 2, kc1 = c1 & 3;
    const size_t gA0 = (size_t)(mBase + r0) * EMB + kc0 * 8;   // fp32 x
    const size_t gA1 = (size_t)(mBase + r1) * EMB + kc1 * 8;
    const size_t gB0 = (size_t)(nBase + r0) * EMB + kc0 * 8;   // bf16 weights
    const size_t gB1 = (size_t)(nBase + r1) * EMB + kc1 * 8;
    const int l0 = (wv * 128) * 8, l1 = (wv * 128 + 64) * 8;

    f32x4 acc[4][4];
    #pragma unroll
    for (int mi = 0; mi < 4; ++mi)
        #pragma unroll
        for (int ni = 0; ni < 4; ++ni)
            acc[mi][ni] = (f32x4){0.f, 0.f, 0.f, 0.f};

    for (int kt = 0; kt < 8; ++kt) {
        const int k0 = kt * 32;
        GLD16(bsh + gB0 + k0, sB + l0);
        GLD16(bsh + gB1 + k0, sB + l1);
        {
            const float4 f0 = *(const float4*)&x[gA0 + k0];
            const float4 f1 = *(const float4*)&x[gA0 + k0 + 4];
            const uint4 p = {pk2(f0.x, f0.y), pk2(f0.z, f0.w),
                             pk2(f1.x, f1.y), pk2(f1.z, f1.w)};
            *(uint4*)&sA[c0 * 8] = p;
        }
        {
            const float4 f0 = *(const float4*)&x[gA1 + k0];
            const float4 f1 = *(const float4*)&x[gA1 + k0 + 4];
            const uint4 p = {pk2(f0.x, f0.y), pk2(f0.z, f0.w),
                             pk2(f1.x, f1.y), pk2(f1.z, f1.w)};
            *(uint4*)&sA[c1 * 8] = p;
        }
        __syncthreads();
        bf16x8 af[4], bf[4];
        #pragma unroll
        for (int mi = 0; mi < 4; ++mi)
            af[mi] = *(const bf16x8*)&sA[(wm + mi * 16 + lrow) * 32 + lqd * 8];
        #pragma unroll
        for (int ni = 0; ni < 4; ++ni)
            bf[ni] = *(const bf16x8*)&sB[(wn + ni * 16 + lrow) * 32 + lqd * 8];
        #pragma unroll
        for (int mi = 0; mi < 4; ++mi)
            #pragma unroll
            for (int ni = 0; ni < 4; ++ni)
                acc[mi][ni] = __builtin_amdgcn_mfma_f32_16x16x32_bf16(af[mi], bf[ni], acc[mi][ni], 0, 0, 0);
        __syncthreads();
    }

    const int which = nBase >> 8;   // 0=q, 1=k, 2=v (uniform)
    const float* bias = (which == 0) ? bq : (which == 1) ? bk : bv;
    u16* dst = (which == 0) ? qb : (which == 1) ? kb : vb;
    #pragma unroll
    for (int ni = 0; ni < 4; ++ni) {
        const int ncol = nBase + wn + ni * 16 + lrow;
        const int c = ncol & 255;
        const float bz = bias[c];
        #pragma unroll
        for (int mi = 0; mi < 4; ++mi) {
            #pragma unroll
            for (int r = 0; r < 4; ++r) {
                const int row = mBase + wm + mi * 16 + lqd * 4 + r;
                dst[(size_t)row * EMB + c] = (u16)bf16_rtne(acc[mi][ni][r] + bz);
            }
        }
    }
}

// ---------------------------------------------------------------------------
// Out-projection, 64x64 tile (grid (4,196) = 784 blocks -> 3.06 waves/SIMD),
// 3-pass split-bf16 (fp32 comparand needs the precision).
// ---------------------------------------------------------------------------
__global__ __launch_bounds__(256) void out_mfma(
    const u16* __restrict__ aoh, const u16* __restrict__ aol,
    const u16* __restrict__ boh, const u16* __restrict__ bol,
    const float* __restrict__ bo, float* __restrict__ out) {
    __shared__ __attribute__((aligned(16))) u16 sAh[64 * 32];
    __shared__ __attribute__((aligned(16))) u16 sAl[64 * 32];
    __shared__ __attribute__((aligned(16))) u16 sBh[64 * 32];
    __shared__ __attribute__((aligned(16))) u16 sBl[64 * 32];
    const int nBase = blockIdx.x * 64;
    const int mBase = blockIdx.y * 64;
    const int tid = threadIdx.x, wv = tid >> 6, ln = tid & 63;
    const int lrow = ln & 15, lqd = ln >> 4;
    const int rA = tid >> 2, kcA = tid & 3;
    const size_t gA = (size_t)(mBase + rA) * EMB + kcA * 8;
    const size_t gB = (size_t)(nBase + rA) * EMB + kcA * 8;
    const int lA = wv * 64 * 8;   // wave-uniform LDS base (chunk = tid)

    f32x4 acc[4];
    #pragma unroll
    for (int mi = 0; mi < 4; ++mi) acc[mi] = (f32x4){0.f, 0.f, 0.f, 0.f};

    for (int kt = 0; kt < 8; ++kt) {
        const int k0 = kt * 32;
        GLD16(aoh + gA + k0, sAh + lA);
        GLD16(aol + gA + k0, sAl + lA);
        GLD16(boh + gB + k0, sBh + lA);
        GLD16(bol + gB + k0, sBl + lA);
        __syncthreads();
        bf16x8 ah[4], al[4];
        #pragma unroll
        for (int mi = 0; mi < 4; ++mi) {
            ah[mi] = *(const bf16x8*)&sAh[(mi * 16 + lrow) * 32 + lqd * 8];
            al[mi] = *(const bf16x8*)&sAl[(mi * 16 + lrow) * 32 + lqd * 8];
        }
        const bf16x8 bh = *(const bf16x8*)&sBh[(wv * 16 + lrow) * 32 + lqd * 8];
        const bf16x8 bl = *(const bf16x8*)&sBl[(wv * 16 + lrow) * 32 + lqd * 8];
        #pragma unroll
        for (int mi = 0; mi < 4; ++mi) {
            acc[mi] = __builtin_amdgcn_mfma_f32_16x16x32_bf16(ah[mi], bh, acc[mi], 0, 0, 0);
            acc[mi] = __builtin_amdgcn_mfma_f32_16x16x32_bf16(al[mi], bh, acc[mi], 0, 0, 0);
            acc[mi] = __builtin_amdgcn_mfma_f32_16x16x32_bf16(ah[mi], bl, acc[mi], 0, 0, 0);
        }
        __syncthreads();
    }

    const int ncol = nBase + wv * 16 + lrow;
    const float bz = bo[ncol];
    #pragma unroll
    for (int mi = 0; mi < 4; ++mi) {
        #pragma unroll
        for (int r = 0; r < 4; ++r) {
            const int row = mBase + mi * 16 + lqd * 4 + r;
            out[(size_t)row * EMB + ncol] = acc[mi][r] + bz;
        }
    }
}

// ---------------------------------------------------------------------------
// Attention (MFMA): block = 256 thr = 4 waves = one (img, 8x8 tile, head).
// LDS 50176 B (3 blocks/CU): sP overlays sK+sV1, both dead after the second
// barrier (every wave's QK reads and transpose reads precede it).
// ---------------------------------------------------------------------------
__global__ __launch_bounds__(256, 3) void attn_kernel(
    const u16* __restrict__ qb, const u16* __restrict__ kb, const u16* __restrict__ vb,
    u16* __restrict__ aoh, u16* __restrict__ aol) {
    __shared__ __attribute__((aligned(16))) u16 smem[25088];   // 50176 B
    u16* sK  = smem;            // [224][KSTR]  K halo, rows>=196 zero
    u16* sV1 = smem + 8960;     // [224][KSTR]  V halo (dead after transpose)
    u16* sVT = smem + 17920;    // [32][VTSTR]  V^T
    u16* sP  = smem;            // [4][16][PSTR] overlays sK+sV1 after barrier 2

    const int tid = threadIdx.x;
    const int w = tid >> 6, ln = tid & 63;
    const int lrow = ln & 15, lqd = ln >> 4;
    const int img = blockIdx.z >> 3, head = blockIdx.z & 7;
    const int ty0 = blockIdx.y * 8, tx0 = blockIdx.x * 8;

    // ---- stage K and V halo [p][dim], OOB/pad rows zero ----
    for (int i = tid; i < 1792; i += 256) {
        const int mv = (i >= 896) ? 1 : 0;
        const int ii = i - 896 * mv;
        const int p = ii >> 2, c = ii & 3;
        const int pyh = p / 14, pxh = p - pyh * 14;
        const int gy = ty0 - 3 + pyh, gx = tx0 - 3 + pxh;
        u16* dst = (mv ? sV1 : sK) + p * KSTR + c * 8;
        if (p < HALO && (unsigned)gy < 56u && (unsigned)gx < 56u) {
            const size_t tt = ((size_t)img * IMG + gy) * IMG + gx;
            *(uint4*)dst = *(const uint4*)((mv ? vb : kb) + tt * EMB + head * 32 + c * 8);
        } else {
            *(uint4*)dst = (uint4){0u, 0u, 0u, 0u};
        }
    }
    __syncthreads();

    // ---- transpose V1 [p][d] -> VT [d][p] (zero pad rows carry over) ----
    for (int i = tid; i < 896; i += 256) {
        const int d = i & 31, ho = i >> 5;          // halo octet 8ho..8ho+7
        u32 pk[4];
        #pragma unroll
        for (int j = 0; j < 4; ++j) {
            const u32 a = sV1[(ho * 8 + 2 * j)     * KSTR + d];
            const u32 b = sV1[(ho * 8 + 2 * j + 1) * KSTR + d];
            pk[j] = a | (b << 16);
        }
        *(uint4*)&sVT[d * VTSTR + ho * 8] = *(uint4*)pk;
    }

    // ---- Q A-fragment straight from global (bf16) ----
    const int mpix = w * 16 + lrow;
    const int qpy = mpix >> 3, qpx = mpix & 7;
    const size_t qtok = ((size_t)img * IMG + ty0 + qpy) * IMG + tx0 + qpx;
    const bf16x8 aq = *(const bf16x8*)&qb[qtok * EMB + head * 32 + lqd * 8];

    // ---- QK: 13 N-tiles over halo 0..207 ----
    f32x4 ct[13];
    #pragma unroll
    for (int t = 0; t < 13; ++t) ct[t] = (f32x4){0.f, 0.f, 0.f, 0.f};
    #pragma unroll
    for (int t = 0; t < 13; ++t) {
        const bf16x8 bk = *(const bf16x8*)&sK[(t * 16 + lrow) * KSTR + lqd * 8];
        ct[t] = __builtin_amdgcn_mfma_f32_16x16x32_bf16(aq, bk, ct[t], 0, 0, 0);
    }

    // ---- mask + softmax in C layout (row = lqd*4+r, col = 16t+lrow) ----
    int pys[4], pxs[4];
    #pragma unroll
    for (int r = 0; r < 4; ++r) {
        const int row = lqd * 4 + r;
        pys[r] = 2 * w + (row >> 3);
        pxs[r] = row & 7;
    }
    float mr4[4] = {-1e30f, -1e30f, -1e30f, -1e30f};
    #pragma unroll
    for (int t = 0; t < 13; ++t) {
        const int col = t * 16 + lrow;
        const int hy = col / 14, hx = col - 14 * hy;
        const bool okc = (col < HALO);
        #pragma unroll
        for (int r = 0; r < 4; ++r) {
            const bool ok = ((unsigned)(hy - pys[r]) < 7u) &
                            ((unsigned)(hx - pxs[r]) < 7u) & okc;
            const float lv = ok ? ct[t][r] * SCALE : -1e30f;
            ct[t][r] = lv;
            mr4[r] = fmaxf(mr4[r], lv);
        }
    }
    #pragma unroll
    for (int r = 0; r < 4; ++r) {
        float m = mr4[r];
        m = fmaxf(m, __shfl_xor(m, 1));
        m = fmaxf(m, __shfl_xor(m, 2));
        m = fmaxf(m, __shfl_xor(m, 4));
        m = fmaxf(m, __shfl_xor(m, 8));
        mr4[r] = m;
    }
    float sr4[4] = {0.f, 0.f, 0.f, 0.f};
    #pragma unroll
    for (int t = 0; t < 13; ++t)
        #pragma unroll
        for (int r = 0; r < 4; ++r) {
            const float e = __expf(ct[t][r] - mr4[r]);
            ct[t][r] = e;
            sr4[r] += e;
        }
    #pragma unroll
    for (int r = 0; r < 4; ++r) {
        float s = sr4[r];
        s += __shfl_xor(s, 1);
        s += __shfl_xor(s, 2);
        s += __shfl_xor(s, 4);
        s += __shfl_xor(s, 8);
        sr4[r] = 1.0f / s;
    }

    __syncthreads();   // sK + sV1 now dead everywhere; safe to overlay with P

    // ---- P (bf16) to LDS; zero cols 208..223 ----
    u16* sPw = sP + w * 16 * PSTR;
    #pragma unroll
    for (int t = 0; t < 13; ++t)
        #pragma unroll
        for (int r = 0; r < 4; ++r)
            sPw[(lqd * 4 + r) * PSTR + t * 16 + lrow] = (u16)bf16_rtne(ct[t][r]);
    #pragma unroll
    for (int z = 0; z < 4; ++z) {
        const int idx = z * 64 + ln;
        sPw[(idx >> 4) * PSTR + 208 + (idx & 15)] = 0;
    }

    // ---- PV: O[16][32] = P[16x224] . VT[32x224]^T ----
    f32x4 o0 = (f32x4){0.f, 0.f, 0.f, 0.f};
    f32x4 o1 = (f32x4){0.f, 0.f, 0.f, 0.f};
    #pragma unroll
    for (int ks = 0; ks < 7; ++ks) {
        const bf16x8 ap  = *(const bf16x8*)&sPw[lrow * PSTR + ks * 32 + lqd * 8];
        const bf16x8 bv0 = *(const bf16x8*)&sVT[lrow * VTSTR + ks * 32 + lqd * 8];
        const bf16x8 bv1 = *(const bf16x8*)&sVT[(16 + lrow) * VTSTR + ks * 32 + lqd * 8];
        o0 = __builtin_amdgcn_mfma_f32_16x16x32_bf16(ap, bv0, o0, 0, 0, 0);
        o1 = __builtin_amdgcn_mfma_f32_16x16x32_bf16(ap, bv1, o1, 0, 0, 0);
    }

    // ---- epilogue: scale by 1/s, split-bf16, store ----
    #pragma unroll
    for (int r = 0; r < 4; ++r) {
        const int row = lqd * 4 + r;
        const int opy = 2 * w + (row >> 3), opx = row & 7;
        const size_t ot = ((size_t)img * IMG + ty0 + opy) * IMG + tx0 + opx;
        const float inv = sr4[r];
        const float v0 = o0[r] * inv;
        const float v1 = o1[r] * inv;
        const size_t base = ot * EMB + head * 32;
        const u32 h0 = bf16_rtne(v0);
        aoh[base + lrow] = (u16)h0;
        aol[base + lrow] = (u16)bf16_rtne(v0 - bf16_to_f(h0));
        const u32 h1 = bf16_rtne(v1);
        aoh[base + 16 + lrow] = (u16)h1;
        aol[base + 16 + lrow] = (u16)bf16_rtne(v1 - bf16_to_f(h1));
    }
}

extern "C" void kernel_launch(void* const* d_in, const int* in_sizes, int n_in,
                              void* d_out, int out_size, void* d_ws, size_t ws_size,
                              hipStream_t stream) {
    const float* x  = (const float*)d_in[0];
    const float* wq = (const float*)d_in[1];
    const float* wk = (const float*)d_in[2];
    const float* wv = (const float*)d_in[3];
    const float* wo = (const float*)d_in[4];
    const float* bq = (const float*)d_in[5];
    const float* bk = (const float*)d_in[6];
    const float* bv = (const float*)d_in[7];
    const float* bo = (const float*)d_in[8];
    float* out = (float*)d_out;

    char* ws = (char*)d_ws;
    u16* qb  = (u16*)(ws);               // 6,422,528 B
    u16* kb  = (u16*)(ws +  6422528);    // 6,422,528 B
    u16* vb  = (u16*)(ws + 12845056);    // 6,422,528 B
    u16* aoh = (u16*)(ws + 19267584);    // 6,422,528 B
    u16* aol = (u16*)(ws + 25690112);    // 6,422,528 B
    u16* bsh = (u16*)(ws + 32112640);    // 393,216 B  stacked qkv weights bf16
    u16* boh = (u16*)(ws + 32505856);    // 131,072 B  wo hi
    u16* bol = (u16*)(ws + 32636928);    // 131,072 B  wo lo -> total 32,768,000 B

    weight_convert<<<256, 256, 0, stream>>>(wq, wk, wv, wo, bsh, boh, bol);
    qkv_mfma<<<dim3(6, 98), 256, 0, stream>>>(x, bsh, bq, bk, bv, qb, kb, vb);
    attn_kernel<<<dim3(7, 7, 32), 256, 0, stream>>>(qb, kb, vb, aoh, aol);
    out_mfma<<<dim3(4, 196), 256, 0, stream>>>(aoh, aol, boh, bol, bo, out);
}